// Round 8
// baseline (7810.904 us; speedup 1.0000x reference)
//
#include <hip/hip_runtime.h>
#include <hip/hip_bf16.h>

#define NP     100000   // n_paths
#define PLEN   5        // path length
#define NLINKS 10000    // n_links
#define DIM    32       // state dim
#define TITERS 8        // message passing iterations
#define E_TOT  (NP * PLEN)

// ---------- helpers ----------
__device__ __forceinline__ float fast_sigmoid(float v) {
    return 1.0f / (1.0f + __expf(-v));
}
__device__ __forceinline__ float fast_tanh(float v) {
    float e = __expf(-2.0f * fabsf(v));
    float t = (1.0f - e) / (1.0f + e);
    return v >= 0.0f ? t : -t;
}
__device__ __forceinline__ float seluf(float v) {
    const float sc = 1.0507009873554805f;
    const float al = 1.6732632423543772f;
    return v > 0.0f ? sc * v : sc * al * (__expf(v) - 1.0f);
}

// ---------- init ----------
__global__ __launch_bounds__(256) void init_kernel(
    const float* __restrict__ cap, const float* __restrict__ pol, const float* __restrict__ wts,
    const float* __restrict__ bw,  const float* __restrict__ tos,
    const float* __restrict__ pk,  const float* __restrict__ avg,
    float* __restrict__ link_state, float* __restrict__ path_state)
{
    int i = blockIdx.x * 256 + threadIdx.x;
    if (i < NLINKS) {
        float row[DIM];
        #pragma unroll
        for (int c = 0; c < DIM; ++c) row[c] = 0.0f;
        row[0] = cap[i]; row[1] = pol[i]; row[2] = wts[i];
        float4* o = (float4*)(link_state + (size_t)i * DIM);
        #pragma unroll
        for (int c = 0; c < 8; ++c) {
            float4 v = { row[4*c], row[4*c+1], row[4*c+2], row[4*c+3] };
            o[c] = v;
        }
    }
    if (i < NP) {
        float row[DIM];
        #pragma unroll
        for (int c = 0; c < DIM; ++c) row[c] = 0.0f;
        row[0] = bw[i]; row[1] = tos[i]; row[2] = pk[i]; row[3] = avg[i];
        float4* o = (float4*)(path_state + (size_t)i * DIM);
        #pragma unroll
        for (int c = 0; c < 8; ++c) {
            float4 v = { row[4*c], row[4*c+1], row[4*c+2], row[4*c+3] };
            o[c] = v;
        }
    }
}

// ---------- CSR build (links launch-invariant) ----------
__global__ __launch_bounds__(256) void csr_count(const int* __restrict__ links,
                                                 int* __restrict__ cnt)
{
    int e = blockIdx.x * 256 + threadIdx.x;
    if (e < E_TOT) atomicAdd(&cnt[links[e]], 1);
}

__global__ __launch_bounds__(256) void csr_scan(const int* __restrict__ cnt,
                                                int* __restrict__ row_start,
                                                int* __restrict__ cursor)
{
    __shared__ int s[256];
    int t = threadIdx.x;
    int carry = 0;
    for (int base = 0; base < NLINKS; base += 256) {
        int i = base + t;
        int v = (i < NLINKS) ? cnt[i] : 0;
        s[t] = v;
        __syncthreads();
        for (int off = 1; off < 256; off <<= 1) {
            int tv = (t >= off) ? s[t - off] : 0;
            __syncthreads();
            s[t] += tv;
            __syncthreads();
        }
        int excl = s[t] - v;
        if (i < NLINKS) { row_start[i] = carry + excl; cursor[i] = carry + excl; }
        int tot = s[255];
        __syncthreads();
        carry += tot;
    }
    if (t == 0) row_start[NLINKS] = carry;   // == E_TOT
}

__global__ __launch_bounds__(256) void csr_scatter(const int* __restrict__ links,
                                                   int* __restrict__ cursor,
                                                   int* __restrict__ eid)
{
    int e = blockIdx.x * 256 + threadIdx.x;
    if (e < E_TOT) {
        int slot = atomicAdd(&cursor[links[e]], 1);
        eid[slot] = e;
    }
}

// ---------- gate precompute: xg = state @ W + b_input  [n,96] ----------
// used for (link_state,Wp,bp) -> xgP and (msg,Wl,bl) -> xgL
__global__ __launch_bounds__(64, 2) void gate_pre_kernel(const float* __restrict__ state,
                                                         const float* __restrict__ W,
                                                         const float* __restrict__ b,
                                                         float* __restrict__ xg, int n)
{
    __shared__ __align__(16) float wS[32 * 96];   // 12 KB
    __shared__ float bS[96];
    int t = threadIdx.x;
    {
        const float4* src = (const float4*)W;
        float4* dst = (float4*)wS;
        #pragma unroll
        for (int i = 0; i < 12; ++i) dst[t + 64 * i] = src[t + 64 * i];
        for (int i = t; i < 96; i += 64) bS[i] = b[i];   // input bias row (row 0)
    }
    __syncthreads();
    int i = blockIdx.x * 64 + t;
    if (i >= n) return;
    float x[DIM];
    {
        const float4* xv = (const float4*)(state + (size_t)i * DIM);
        #pragma unroll
        for (int c = 0; c < 8; ++c) {
            float4 v = xv[c];
            x[4*c] = v.x; x[4*c+1] = v.y; x[4*c+2] = v.z; x[4*c+3] = v.w;
        }
    }
    #pragma unroll
    for (int g = 0; g < 3; ++g) {
        float acc[DIM];
        #pragma unroll
        for (int j = 0; j < DIM; ++j) acc[j] = bS[g * 32 + j];
        #pragma unroll
        for (int k = 0; k < DIM; ++k) {
            float xk = x[k];
            const float4* wv = (const float4*)&wS[k * 96 + g * 32];
            #pragma unroll
            for (int q = 0; q < 8; ++q) {
                float4 u = wv[q];
                acc[4*q]   += xk * u.x;
                acc[4*q+1] += xk * u.y;
                acc[4*q+2] += xk * u.z;
                acc[4*q+3] += xk * u.w;
            }
        }
        float4* o = (float4*)&xg[(size_t)i * 96 + g * 32];
        #pragma unroll
        for (int c = 0; c < 8; ++c) {
            float4 v = { acc[4*c], acc[4*c+1], acc[4*c+2], acc[4*c+3] };
            o[c] = v;
        }
    }
}

// ---------- half-GRU step: 2 lanes per row, each owns 16 columns ----------
// xr: 96 gate pre-activations (x@W+b0) for this row. uS: U staged in LDS
// (row-major 32x96). bS: recurrent bias row (96). Full h[32] in regs in both
// lanes; after update both lanes hold the new full h (shuffle exchange).
// Gate order r -> n -> z keeps peak live ~100 floats (no spill at any
// plausible VGPR budget; R7's 128-budget spill was the 5480us regression).
__device__ __forceinline__ void gru_half(const float* __restrict__ xr,
                                         const float* __restrict__ uS,
                                         const float* __restrict__ bS,
                                         int jb, float (&h)[DIM], float (&newh)[16])
{
    float acc[16];
    // ---- r gate (cols 32+jb .. 32+jb+16) ----
    {
        const float4* a = (const float4*)(xr + 32 + jb);
        #pragma unroll
        for (int q = 0; q < 4; ++q) {
            float4 v = a[q];
            acc[4*q]   = v.x + bS[32 + jb + 4*q];
            acc[4*q+1] = v.y + bS[32 + jb + 4*q+1];
            acc[4*q+2] = v.z + bS[32 + jb + 4*q+2];
            acc[4*q+3] = v.w + bS[32 + jb + 4*q+3];
        }
    }
    #pragma unroll
    for (int k = 0; k < DIM; ++k) {
        float hk = h[k];
        const float4* u4 = (const float4*)&uS[k * 96 + 32 + jb];
        #pragma unroll
        for (int q = 0; q < 4; ++q) {
            float4 u = u4[q];
            acc[4*q]   += hk * u.x;
            acc[4*q+1] += hk * u.y;
            acc[4*q+2] += hk * u.z;
            acc[4*q+3] += hk * u.w;
        }
    }
    float r[16];
    #pragma unroll
    for (int j = 0; j < 16; ++j) r[j] = fast_sigmoid(acc[j]);

    // ---- n gate recurrent (cols 64+jb) ----
    #pragma unroll
    for (int j = 0; j < 16; ++j) acc[j] = bS[64 + jb + j];
    #pragma unroll
    for (int k = 0; k < DIM; ++k) {
        float hk = h[k];
        const float4* u4 = (const float4*)&uS[k * 96 + 64 + jb];
        #pragma unroll
        for (int q = 0; q < 4; ++q) {
            float4 u = u4[q];
            acc[4*q]   += hk * u.x;
            acc[4*q+1] += hk * u.y;
            acc[4*q+2] += hk * u.z;
            acc[4*q+3] += hk * u.w;
        }
    }
    float hn[16];
    {
        const float4* a = (const float4*)(xr + 64 + jb);
        #pragma unroll
        for (int q = 0; q < 4; ++q) {
            float4 v = a[q];
            hn[4*q]   = fast_tanh(v.x + r[4*q]   * acc[4*q]);
            hn[4*q+1] = fast_tanh(v.y + r[4*q+1] * acc[4*q+1]);
            hn[4*q+2] = fast_tanh(v.z + r[4*q+2] * acc[4*q+2]);
            hn[4*q+3] = fast_tanh(v.w + r[4*q+3] * acc[4*q+3]);
        }
    }

    // ---- z gate (cols jb) ----
    {
        const float4* a = (const float4*)(xr + jb);
        #pragma unroll
        for (int q = 0; q < 4; ++q) {
            float4 v = a[q];
            acc[4*q]   = v.x + bS[jb + 4*q];
            acc[4*q+1] = v.y + bS[jb + 4*q+1];
            acc[4*q+2] = v.z + bS[jb + 4*q+2];
            acc[4*q+3] = v.w + bS[jb + 4*q+3];
        }
    }
    #pragma unroll
    for (int k = 0; k < DIM; ++k) {
        float hk = h[k];
        const float4* u4 = (const float4*)&uS[k * 96 + jb];
        #pragma unroll
        for (int q = 0; q < 4; ++q) {
            float4 u = u4[q];
            acc[4*q]   += hk * u.x;
            acc[4*q+1] += hk * u.y;
            acc[4*q+2] += hk * u.z;
            acc[4*q+3] += hk * u.w;
        }
    }
    #pragma unroll
    for (int j = 0; j < 16; ++j) {
        float z = fast_sigmoid(acc[j]);
        newh[j] = z * h[jb + j] + (1.0f - z) * hn[j];
    }

    // ---- exchange halves within the lane pair ----
    float other[16];
    #pragma unroll
    for (int j = 0; j < 16; ++j) other[j] = __shfl_xor(newh[j], 1);
    int half = jb >> 4;
    #pragma unroll
    for (int j = 0; j < DIM; ++j)
        h[j] = ((j >> 4) == half) ? newh[j & 15] : other[j & 15];
}

// ---------- path GRU over 5 hops (2 lanes/path); per-hop h -> m[E,32] ----------
template <bool STORE_M>
__global__ __launch_bounds__(64, 2) void path_kernel(
    const int*   __restrict__ links,
    const float* __restrict__ xg,
    const float* __restrict__ Up, const float* __restrict__ bp,
    float* __restrict__ path_state,
    float* __restrict__ m)
{
    __shared__ __align__(16) float uS[32 * 96];   // 12 KB
    __shared__ float bS[96];                      // recurrent bias row
    int t = threadIdx.x;
    {
        const float4* src = (const float4*)Up;
        float4* dst = (float4*)uS;
        #pragma unroll
        for (int i = 0; i < 12; ++i) dst[t + 64 * i] = src[t + 64 * i];
        for (int i = t; i < 96; i += 64) bS[i] = bp[96 + i];
    }
    __syncthreads();
    int slot = t >> 1, half = t & 1, jb = half * 16;
    int p = blockIdx.x * 32 + slot;               // NP % 32 == 0, all active

    float h[DIM];
    {
        const float4* hv = (const float4*)(path_state + (size_t)p * DIM);
        #pragma unroll
        for (int i = 0; i < 8; ++i) {
            float4 v = hv[i];
            h[4*i] = v.x; h[4*i+1] = v.y; h[4*i+2] = v.z; h[4*i+3] = v.w;
        }
    }
    int lk[PLEN];
    #pragma unroll
    for (int l = 0; l < PLEN; ++l) lk[l] = links[p * PLEN + l];

    float newh[16];
    #pragma unroll 1
    for (int l = 0; l < PLEN; ++l) {
        gru_half(xg + (size_t)lk[l] * 96, uS, bS, jb, h, newh);
        if (STORE_M) {
            float4* m4 = (float4*)(m + (size_t)(p * PLEN + l) * DIM + jb);
            #pragma unroll
            for (int q = 0; q < 4; ++q) {
                float4 v = { newh[4*q], newh[4*q+1], newh[4*q+2], newh[4*q+3] };
                m4[q] = v;
            }
        }
    }
    float4* ho = (float4*)(path_state + (size_t)p * DIM + jb);
    #pragma unroll
    for (int q = 0; q < 4; ++q) {
        float4 v = { newh[4*q], newh[4*q+1], newh[4*q+2], newh[4*q+3] };
        ho[q] = v;
    }
}

// ---------- link GRU step (2 lanes/link), consumes xgL = msg@Wl + bl0 ----------
__global__ __launch_bounds__(64, 2) void link_kernel(
    const float* __restrict__ xgL,
    const float* __restrict__ Ul, const float* __restrict__ bl,
    float* __restrict__ link_state)
{
    __shared__ __align__(16) float uS[32 * 96];   // 12 KB
    __shared__ float bS[96];
    int t = threadIdx.x;
    {
        const float4* src = (const float4*)Ul;
        float4* dst = (float4*)uS;
        #pragma unroll
        for (int i = 0; i < 12; ++i) dst[t + 64 * i] = src[t + 64 * i];
        for (int i = t; i < 96; i += 64) bS[i] = bl[96 + i];
    }
    __syncthreads();
    int slot = t >> 1, half = t & 1, jb = half * 16;
    int i = blockIdx.x * 32 + slot;
    if (i >= NLINKS) return;                      // pairs co-active

    float h[DIM];
    {
        const float4* hv = (const float4*)(link_state + (size_t)i * DIM);
        #pragma unroll
        for (int c = 0; c < 8; ++c) {
            float4 v = hv[c];
            h[4*c] = v.x; h[4*c+1] = v.y; h[4*c+2] = v.z; h[4*c+3] = v.w;
        }
    }
    float newh[16];
    gru_half(xgL + (size_t)i * 96, uS, bS, jb, h, newh);
    float4* ho = (float4*)(link_state + (size_t)i * DIM + jb);
    #pragma unroll
    for (int q = 0; q < 4; ++q) {
        float4 v = { newh[4*q], newh[4*q+1], newh[4*q+2], newh[4*q+3] };
        ho[q] = v;
    }
}

// ---------- CSR gather: msg[link] = sum over entries of m[e] ----------
__global__ __launch_bounds__(256) void agg_kernel(
    const int* __restrict__ row_start, const int* __restrict__ eid,
    const float* __restrict__ m, float* __restrict__ msg)
{
    int gid  = blockIdx.x * 256 + threadIdx.x;
    int link = gid >> 6;
    int lane = threadIdx.x & 63;
    if (link >= NLINKS) return;
    int s0 = row_start[link], s1 = row_start[link + 1];
    int half = lane >> 5, d = lane & 31;
    float v = 0.0f;
    for (int i = s0 + half; i < s1; i += 2) {
        int e = eid[i];
        v += m[(size_t)e * DIM + d];
    }
    v += __shfl_down(v, 32);
    if (lane < 32) msg[(size_t)link * DIM + d] = v;
}

// ---------- readout MLP: 32 -> 256 (selu) -> 256 (selu) -> 1 ----------
__global__ __launch_bounds__(256) void readout_kernel(
    const float* __restrict__ path_state,
    const float* __restrict__ R1, const float* __restrict__ Rb1,
    const float* __restrict__ R2, const float* __restrict__ Rb2,
    const float* __restrict__ R3, const float* __restrict__ Rb3,
    float* __restrict__ out)
{
    const int PB  = 32;
    const int STR = 260;                 // h1 row stride (floats)
    __shared__ float h0s[PB * DIM];
    __shared__ float h1s[PB * STR];
    __shared__ float outAcc[PB];
    int t  = threadIdx.x;
    int p0 = blockIdx.x * PB;

    for (int i = t; i < PB * DIM; i += 256)
        h0s[i] = path_state[(size_t)p0 * DIM + i];
    if (t < PB) outAcc[t] = 0.0f;
    __syncthreads();

    {
        int j = t;
        float r1[DIM];
        #pragma unroll
        for (int k = 0; k < DIM; ++k) r1[k] = R1[k * 256 + j];
        float bj = Rb1[j];
        for (int p = 0; p < PB; ++p) {
            float s = bj;
            #pragma unroll
            for (int k = 0; k < DIM; ++k) s += h0s[p * DIM + k] * r1[k];
            h1s[p * STR + j] = seluf(s);
        }
    }
    __syncthreads();

    int tj = t & 31, tp = t >> 5;
    int j0 = tj * 8, pp0 = tp * 4;
    float acc[4][8];
    #pragma unroll
    for (int pi = 0; pi < 4; ++pi)
        #pragma unroll
        for (int ji = 0; ji < 8; ++ji) acc[pi][ji] = Rb2[j0 + ji];

    for (int k = 0; k < 256; k += 4) {
        float xv[4][4];
        #pragma unroll
        for (int pi = 0; pi < 4; ++pi) {
            float4 v = *(const float4*)&h1s[(pp0 + pi) * STR + k];
            xv[pi][0] = v.x; xv[pi][1] = v.y; xv[pi][2] = v.z; xv[pi][3] = v.w;
        }
        #pragma unroll
        for (int kk = 0; kk < 4; ++kk) {
            float wv[8];
            #pragma unroll
            for (int ji = 0; ji < 8; ++ji) wv[ji] = R2[(k + kk) * 256 + j0 + ji];
            #pragma unroll
            for (int pi = 0; pi < 4; ++pi)
                #pragma unroll
                for (int ji = 0; ji < 8; ++ji)
                    acc[pi][ji] += xv[pi][kk] * wv[ji];
        }
    }

    float r3[8];
    #pragma unroll
    for (int ji = 0; ji < 8; ++ji) r3[ji] = R3[j0 + ji];
    #pragma unroll
    for (int pi = 0; pi < 4; ++pi) {
        float s = 0.0f;
        #pragma unroll
        for (int ji = 0; ji < 8; ++ji) s += seluf(acc[pi][ji]) * r3[ji];
        atomicAdd(&outAcc[pp0 + pi], s);
    }
    __syncthreads();
    if (t < PB) out[p0 + t] = outAcc[t] + Rb3[0];
}

extern "C" void kernel_launch(void* const* d_in, const int* in_sizes, int n_in,
                              void* d_out, int out_size, void* d_ws, size_t ws_size,
                              hipStream_t stream)
{
    const int*   links = (const int*)d_in[0];
    const float* cap = (const float*)d_in[3];
    const float* pol = (const float*)d_in[4];
    const float* wts = (const float*)d_in[5];
    const float* bw  = (const float*)d_in[6];
    const float* tos = (const float*)d_in[7];
    const float* pk  = (const float*)d_in[8];
    const float* avg = (const float*)d_in[9];
    const float* Wp  = (const float*)d_in[10];
    const float* Up  = (const float*)d_in[11];
    const float* bp  = (const float*)d_in[12];
    const float* Wl  = (const float*)d_in[13];
    const float* Ul  = (const float*)d_in[14];
    const float* bl  = (const float*)d_in[15];
    const float* R1  = (const float*)d_in[16];
    const float* Rb1 = (const float*)d_in[17];
    const float* R2  = (const float*)d_in[18];
    const float* Rb2 = (const float*)d_in[19];
    const float* R3  = (const float*)d_in[20];
    const float* Rb3 = (const float*)d_in[21];

    // workspace layout (256B aligned chunks), ~90 MB total
    char* w = (char*)d_ws;
    size_t off = 0;
    auto alloc = [&](size_t bytes) {
        char* p = w + off;
        off += (bytes + 255) & ~(size_t)255;
        return p;
    };
    float* path_state = (float*)alloc((size_t)NP * DIM * 4);        // 12.8 MB
    float* link_state = (float*)alloc((size_t)NLINKS * DIM * 4);    // 1.28 MB
    float* msg        = (float*)alloc((size_t)NLINKS * DIM * 4);    // 1.28 MB
    float* xgP        = (float*)alloc((size_t)NLINKS * 96 * 4);     // 3.84 MB
    float* xgL        = (float*)alloc((size_t)NLINKS * 96 * 4);     // 3.84 MB
    float* m          = (float*)alloc((size_t)E_TOT * DIM * 4);     // 64 MB
    int*   cnt        = (int*)alloc((size_t)NLINKS * 4);
    int*   row_start  = (int*)alloc((size_t)(NLINKS + 1) * 4);
    int*   cursor     = (int*)alloc((size_t)NLINKS * 4);
    int*   eid        = (int*)alloc((size_t)E_TOT * 4);             // 2 MB

    init_kernel<<<(NP + 255) / 256, 256, 0, stream>>>(cap, pol, wts, bw, tos, pk, avg,
                                                      link_state, path_state);
    // CSR (links constant across iterations -> build once per launch)
    hipMemsetAsync(cnt, 0, (size_t)NLINKS * 4, stream);
    csr_count  <<<(E_TOT + 255) / 256, 256, 0, stream>>>(links, cnt);
    csr_scan   <<<1, 256, 0, stream>>>(cnt, row_start, cursor);
    csr_scatter<<<(E_TOT + 255) / 256, 256, 0, stream>>>(links, cursor, eid);

    const int LGRID = (NLINKS + 63) / 64;                 // gate_pre grid
    const int LGRID2 = (NLINKS + 31) / 32;                // 2-lane link grid
    for (int it = 0; it < TITERS; ++it) {
        gate_pre_kernel<<<LGRID, 64, 0, stream>>>(link_state, Wp, bp, xgP, NLINKS);
        if (it < TITERS - 1) {
            path_kernel<true><<<NP / 32, 64, 0, stream>>>(links, xgP, Up, bp,
                                                          path_state, m);
            agg_kernel<<<(NLINKS * 64 + 255) / 256, 256, 0, stream>>>(row_start, eid, m, msg);
            gate_pre_kernel<<<LGRID, 64, 0, stream>>>(msg, Wl, bl, xgL, NLINKS);
            link_kernel<<<LGRID2, 64, 0, stream>>>(xgL, Ul, bl, link_state);
        } else {
            // last iteration: link update is dead (readout reads only path_state)
            path_kernel<false><<<NP / 32, 64, 0, stream>>>(links, xgP, Up, bp,
                                                           path_state, m);
        }
    }
    readout_kernel<<<NP / 32, 256, 0, stream>>>(path_state, R1, Rb1, R2, Rb2, R3, Rb3,
                                                (float*)d_out);
}

// Round 9
// 6283.438 us; speedup vs baseline: 1.2431x; 1.2431x over previous
//
#include <hip/hip_runtime.h>
#include <hip/hip_bf16.h>

#define NP     100000   // n_paths
#define PLEN   5        // path length
#define NLINKS 10000    // n_links
#define DIM    32       // state dim
#define TITERS 8        // message passing iterations
#define E_TOT  (NP * PLEN)

// ---------- helpers ----------
__device__ __forceinline__ float fast_sigmoid(float v) {
    return 1.0f / (1.0f + __expf(-v));
}
__device__ __forceinline__ float fast_tanh(float v) {
    float e = __expf(-2.0f * fabsf(v));
    float t = (1.0f - e) / (1.0f + e);
    return v >= 0.0f ? t : -t;
}
__device__ __forceinline__ float seluf(float v) {
    const float sc = 1.0507009873554805f;
    const float al = 1.6732632423543772f;
    return v > 0.0f ? sc * v : sc * al * (__expf(v) - 1.0f);
}

// ---------- init ----------
__global__ __launch_bounds__(256) void init_kernel(
    const float* __restrict__ cap, const float* __restrict__ pol, const float* __restrict__ wts,
    const float* __restrict__ bw,  const float* __restrict__ tos,
    const float* __restrict__ pk,  const float* __restrict__ avg,
    float* __restrict__ link_state, float* __restrict__ path_state)
{
    int i = blockIdx.x * 256 + threadIdx.x;
    if (i < NLINKS) {
        float row[DIM];
        #pragma unroll
        for (int c = 0; c < DIM; ++c) row[c] = 0.0f;
        row[0] = cap[i]; row[1] = pol[i]; row[2] = wts[i];
        float4* o = (float4*)(link_state + (size_t)i * DIM);
        #pragma unroll
        for (int c = 0; c < 8; ++c) {
            float4 v = { row[4*c], row[4*c+1], row[4*c+2], row[4*c+3] };
            o[c] = v;
        }
    }
    if (i < NP) {
        float row[DIM];
        #pragma unroll
        for (int c = 0; c < DIM; ++c) row[c] = 0.0f;
        row[0] = bw[i]; row[1] = tos[i]; row[2] = pk[i]; row[3] = avg[i];
        float4* o = (float4*)(path_state + (size_t)i * DIM);
        #pragma unroll
        for (int c = 0; c < 8; ++c) {
            float4 v = { row[4*c], row[4*c+1], row[4*c+2], row[4*c+3] };
            o[c] = v;
        }
    }
}

// ---------- CSR build (links launch-invariant) ----------
__global__ __launch_bounds__(256) void csr_count(const int* __restrict__ links,
                                                 int* __restrict__ cnt)
{
    int e = blockIdx.x * 256 + threadIdx.x;
    if (e < E_TOT) atomicAdd(&cnt[links[e]], 1);
}

__global__ __launch_bounds__(256) void csr_scan(const int* __restrict__ cnt,
                                                int* __restrict__ row_start,
                                                int* __restrict__ cursor)
{
    __shared__ int s[256];
    int t = threadIdx.x;
    int carry = 0;
    for (int base = 0; base < NLINKS; base += 256) {
        int i = base + t;
        int v = (i < NLINKS) ? cnt[i] : 0;
        s[t] = v;
        __syncthreads();
        for (int off = 1; off < 256; off <<= 1) {
            int tv = (t >= off) ? s[t - off] : 0;
            __syncthreads();
            s[t] += tv;
            __syncthreads();
        }
        int excl = s[t] - v;
        if (i < NLINKS) { row_start[i] = carry + excl; cursor[i] = carry + excl; }
        int tot = s[255];
        __syncthreads();
        carry += tot;
    }
    if (t == 0) row_start[NLINKS] = carry;   // == E_TOT
}

__global__ __launch_bounds__(256) void csr_scatter(const int* __restrict__ links,
                                                   int* __restrict__ cursor,
                                                   int* __restrict__ eid)
{
    int e = blockIdx.x * 256 + threadIdx.x;
    if (e < E_TOT) {
        int slot = atomicAdd(&cursor[links[e]], 1);
        eid[slot] = e;
    }
}

// ---------- per-iteration: xg = link_state @ Wp + bp[0]  [NL,96] ----------
// Wp staged in LDS; block 256, loose bounds (256,1) -> no forced VGPR tier.
__global__ __launch_bounds__(256, 1) void xg_kernel(const float* __restrict__ link_state,
                                                    const float* __restrict__ Wp,
                                                    const float* __restrict__ bp,
                                                    float* __restrict__ xg)
{
    __shared__ __align__(16) float wS[32 * 96];   // 12 KB
    __shared__ float bS[96];
    int t = threadIdx.x;
    {
        const float4* src = (const float4*)Wp;    // 768 float4
        float4* dst = (float4*)wS;
        #pragma unroll
        for (int i = 0; i < 3; ++i) dst[t + 256 * i] = src[t + 256 * i];
        if (t < 96) bS[t] = bp[t];                // input bias row
    }
    __syncthreads();
    int i = blockIdx.x * 256 + t;
    if (i >= NLINKS) return;
    float x[DIM];
    {
        const float4* xv = (const float4*)(link_state + (size_t)i * DIM);
        #pragma unroll
        for (int c = 0; c < 8; ++c) {
            float4 v = xv[c];
            x[4*c] = v.x; x[4*c+1] = v.y; x[4*c+2] = v.z; x[4*c+3] = v.w;
        }
    }
    #pragma unroll
    for (int g = 0; g < 3; ++g) {
        float acc[DIM];
        #pragma unroll
        for (int j = 0; j < DIM; ++j) acc[j] = bS[g * 32 + j];
        #pragma unroll
        for (int k = 0; k < DIM; ++k) {
            float xk = x[k];
            const float4* wv = (const float4*)&wS[k * 96 + g * 32];
            #pragma unroll
            for (int q = 0; q < 8; ++q) {
                float4 u = wv[q];
                acc[4*q]   += xk * u.x;
                acc[4*q+1] += xk * u.y;
                acc[4*q+2] += xk * u.z;
                acc[4*q+3] += xk * u.w;
            }
        }
        float4* o = (float4*)&xg[(size_t)i * 96 + g * 32];
        #pragma unroll
        for (int c = 0; c < 8; ++c) {
            float4 v = { acc[4*c], acc[4*c+1], acc[4*c+2], acc[4*c+3] };
            o[c] = v;
        }
    }
}

// ---------- path GRU over 5 hops; per-hop h -> m[E,32] (f32) ----------
// EXACT R6 structure (sequential z,r,n; compile-time indices; block 256,
// bounds (256,1) -> VGPR 112, no scratch) with ONE change: Up/bp(rec) come
// from LDS (wave-uniform ds_read broadcast) instead of s_load-streamed global.
// R7/R8 lesson: (64,2) caps VGPR at 128 and spills; runtime-indexed register
// arrays demote to scratch -> GBs of thrash. Neither is present here.
template <bool STORE_M>
__global__ __launch_bounds__(256, 1) void path_kernel(
    const int*   __restrict__ links,
    const float* __restrict__ xg,
    const float* __restrict__ Up, const float* __restrict__ bp,
    float* __restrict__ path_state,
    float* __restrict__ m)
{
    __shared__ __align__(16) float uS[32 * 96];   // 12 KB
    __shared__ float bS[96];                      // recurrent bias row
    int t = threadIdx.x;
    {
        const float4* src = (const float4*)Up;    // 768 float4
        float4* dst = (float4*)uS;
        #pragma unroll
        for (int i = 0; i < 3; ++i) dst[t + 256 * i] = src[t + 256 * i];
        if (t < 96) bS[t] = bp[96 + t];
    }
    __syncthreads();
    int p = blockIdx.x * 256 + t;
    if (p >= NP) return;

    float h[DIM];
    {
        const float4* hv = (const float4*)(path_state + (size_t)p * DIM);
        #pragma unroll
        for (int i = 0; i < 8; ++i) {
            float4 v = hv[i];
            h[4*i] = v.x; h[4*i+1] = v.y; h[4*i+2] = v.z; h[4*i+3] = v.w;
        }
    }
    #pragma unroll 1
    for (int l = 0; l < PLEN; ++l) {
        int link = links[p * PLEN + l];
        const float* xr = xg + (size_t)link * 96;
        float acc[DIM], z[DIM], r[DIM];

        // ---- z gate ----
        #pragma unroll
        for (int i = 0; i < 8; ++i) {
            float4 v = ((const float4*)xr)[i];
            acc[4*i]   = v.x + bS[4*i];
            acc[4*i+1] = v.y + bS[4*i+1];
            acc[4*i+2] = v.z + bS[4*i+2];
            acc[4*i+3] = v.w + bS[4*i+3];
        }
        #pragma unroll
        for (int k = 0; k < DIM; ++k) {
            float hk = h[k];
            const float4* u4 = (const float4*)&uS[k * 96];
            #pragma unroll
            for (int q = 0; q < 8; ++q) {
                float4 u = u4[q];
                acc[4*q]   += hk * u.x;
                acc[4*q+1] += hk * u.y;
                acc[4*q+2] += hk * u.z;
                acc[4*q+3] += hk * u.w;
            }
        }
        #pragma unroll
        for (int j = 0; j < DIM; ++j) z[j] = fast_sigmoid(acc[j]);

        // ---- r gate ----
        #pragma unroll
        for (int i = 0; i < 8; ++i) {
            float4 v = ((const float4*)(xr + 32))[i];
            acc[4*i]   = v.x + bS[32 + 4*i];
            acc[4*i+1] = v.y + bS[32 + 4*i+1];
            acc[4*i+2] = v.z + bS[32 + 4*i+2];
            acc[4*i+3] = v.w + bS[32 + 4*i+3];
        }
        #pragma unroll
        for (int k = 0; k < DIM; ++k) {
            float hk = h[k];
            const float4* u4 = (const float4*)&uS[k * 96 + 32];
            #pragma unroll
            for (int q = 0; q < 8; ++q) {
                float4 u = u4[q];
                acc[4*q]   += hk * u.x;
                acc[4*q+1] += hk * u.y;
                acc[4*q+2] += hk * u.z;
                acc[4*q+3] += hk * u.w;
            }
        }
        #pragma unroll
        for (int j = 0; j < DIM; ++j) r[j] = fast_sigmoid(acc[j]);

        // ---- n gate recurrent part ----
        #pragma unroll
        for (int j = 0; j < DIM; ++j) acc[j] = bS[64 + j];
        #pragma unroll
        for (int k = 0; k < DIM; ++k) {
            float hk = h[k];
            const float4* u4 = (const float4*)&uS[k * 96 + 64];
            #pragma unroll
            for (int q = 0; q < 8; ++q) {
                float4 u = u4[q];
                acc[4*q]   += hk * u.x;
                acc[4*q+1] += hk * u.y;
                acc[4*q+2] += hk * u.z;
                acc[4*q+3] += hk * u.w;
            }
        }
        // stream xn, finish hn, update h
        #pragma unroll
        for (int i = 0; i < 8; ++i) {
            float4 v = ((const float4*)(xr + 64))[i];
            float hn0 = fast_tanh(v.x + r[4*i]   * acc[4*i]);
            float hn1 = fast_tanh(v.y + r[4*i+1] * acc[4*i+1]);
            float hn2 = fast_tanh(v.z + r[4*i+2] * acc[4*i+2]);
            float hn3 = fast_tanh(v.w + r[4*i+3] * acc[4*i+3]);
            h[4*i]   = z[4*i]   * h[4*i]   + (1.0f - z[4*i])   * hn0;
            h[4*i+1] = z[4*i+1] * h[4*i+1] + (1.0f - z[4*i+1]) * hn1;
            h[4*i+2] = z[4*i+2] * h[4*i+2] + (1.0f - z[4*i+2]) * hn2;
            h[4*i+3] = z[4*i+3] * h[4*i+3] + (1.0f - z[4*i+3]) * hn3;
        }

        if (STORE_M) {
            float4* m4 = (float4*)(m + (size_t)(p * PLEN + l) * DIM);
            #pragma unroll
            for (int i = 0; i < 8; ++i) {
                float4 v = { h[4*i], h[4*i+1], h[4*i+2], h[4*i+3] };
                m4[i] = v;
            }
        }
    }
    float4* ho = (float4*)(path_state + (size_t)p * DIM);
    #pragma unroll
    for (int i = 0; i < 8; ++i) {
        float4 v = { h[4*i], h[4*i+1], h[4*i+2], h[4*i+3] };
        ho[i] = v;
    }
}

// ---------- CSR gather: msg[link] = sum over entries of m[e] ----------
__global__ __launch_bounds__(256) void agg_kernel(
    const int* __restrict__ row_start, const int* __restrict__ eid,
    const float* __restrict__ m, float* __restrict__ msg)
{
    int gid  = blockIdx.x * 256 + threadIdx.x;
    int link = gid >> 6;
    int lane = threadIdx.x & 63;
    if (link >= NLINKS) return;
    int s0 = row_start[link], s1 = row_start[link + 1];
    int half = lane >> 5, d = lane & 31;
    float v = 0.0f;
    for (int i = s0 + half; i < s1; i += 2) {
        int e = eid[i];
        v += m[(size_t)e * DIM + d];
    }
    v += __shfl_down(v, 32);
    if (lane < 32) msg[(size_t)link * DIM + d] = v;
}

// ---------- link GRU (Wl + Ul + biases staged in LDS; R6 structure) ----------
__global__ __launch_bounds__(256, 1) void link_kernel(
    const float* __restrict__ Wl, const float* __restrict__ Ul, const float* __restrict__ bl,
    const float* __restrict__ msg,
    float* __restrict__ link_state)
{
    __shared__ __align__(16) float wS[32 * 96];   // 12 KB
    __shared__ __align__(16) float uS[32 * 96];   // 12 KB
    __shared__ float bS[192];
    int t = threadIdx.x;
    {
        const float4* srcW = (const float4*)Wl;
        const float4* srcU = (const float4*)Ul;
        float4* dstW = (float4*)wS;
        float4* dstU = (float4*)uS;
        #pragma unroll
        for (int i = 0; i < 3; ++i) {
            dstW[t + 256 * i] = srcW[t + 256 * i];
            dstU[t + 256 * i] = srcU[t + 256 * i];
        }
        if (t < 192) bS[t] = bl[t];
    }
    __syncthreads();
    int i = blockIdx.x * 256 + t;
    if (i >= NLINKS) return;
    float h[DIM], x[DIM];
    {
        const float4* xv = (const float4*)(msg + (size_t)i * DIM);
        const float4* hv = (const float4*)(link_state + (size_t)i * DIM);
        #pragma unroll
        for (int c = 0; c < 8; ++c) {
            float4 a = xv[c];
            x[4*c] = a.x; x[4*c+1] = a.y; x[4*c+2] = a.z; x[4*c+3] = a.w;
            float4 b2 = hv[c];
            h[4*c] = b2.x; h[4*c+1] = b2.y; h[4*c+2] = b2.z; h[4*c+3] = b2.w;
        }
    }
    float acc[DIM], z[DIM], r[DIM];

    // z
    #pragma unroll
    for (int j = 0; j < DIM; ++j) acc[j] = bS[j] + bS[96 + j];
    #pragma unroll
    for (int k = 0; k < DIM; ++k) {
        float xk = x[k], hk = h[k];
        const float4* w4 = (const float4*)&wS[k * 96];
        const float4* u4 = (const float4*)&uS[k * 96];
        #pragma unroll
        for (int q = 0; q < 8; ++q) {
            float4 wv = w4[q], uv = u4[q];
            acc[4*q]   += xk * wv.x + hk * uv.x;
            acc[4*q+1] += xk * wv.y + hk * uv.y;
            acc[4*q+2] += xk * wv.z + hk * uv.z;
            acc[4*q+3] += xk * wv.w + hk * uv.w;
        }
    }
    #pragma unroll
    for (int j = 0; j < DIM; ++j) z[j] = fast_sigmoid(acc[j]);

    // r
    #pragma unroll
    for (int j = 0; j < DIM; ++j) acc[j] = bS[32 + j] + bS[96 + 32 + j];
    #pragma unroll
    for (int k = 0; k < DIM; ++k) {
        float xk = x[k], hk = h[k];
        const float4* w4 = (const float4*)&wS[k * 96 + 32];
        const float4* u4 = (const float4*)&uS[k * 96 + 32];
        #pragma unroll
        for (int q = 0; q < 8; ++q) {
            float4 wv = w4[q], uv = u4[q];
            acc[4*q]   += xk * wv.x + hk * uv.x;
            acc[4*q+1] += xk * wv.y + hk * uv.y;
            acc[4*q+2] += xk * wv.z + hk * uv.z;
            acc[4*q+3] += xk * wv.w + hk * uv.w;
        }
    }
    #pragma unroll
    for (int j = 0; j < DIM; ++j) r[j] = fast_sigmoid(acc[j]);

    // n: xn and hg separate (hn = tanh(xn + r*hg))
    float accx[DIM];
    #pragma unroll
    for (int j = 0; j < DIM; ++j) { accx[j] = bS[64 + j]; acc[j] = bS[96 + 64 + j]; }
    #pragma unroll
    for (int k = 0; k < DIM; ++k) {
        float xk = x[k], hk = h[k];
        const float4* w4 = (const float4*)&wS[k * 96 + 64];
        const float4* u4 = (const float4*)&uS[k * 96 + 64];
        #pragma unroll
        for (int q = 0; q < 8; ++q) {
            float4 wv = w4[q], uv = u4[q];
            accx[4*q]   += xk * wv.x;  acc[4*q]   += hk * uv.x;
            accx[4*q+1] += xk * wv.y;  acc[4*q+1] += hk * uv.y;
            accx[4*q+2] += xk * wv.z;  acc[4*q+2] += hk * uv.z;
            accx[4*q+3] += xk * wv.w;  acc[4*q+3] += hk * uv.w;
        }
    }
    #pragma unroll
    for (int j = 0; j < DIM; ++j) {
        float hn = fast_tanh(accx[j] + r[j] * acc[j]);
        h[j] = z[j] * h[j] + (1.0f - z[j]) * hn;
    }

    float4* ho = (float4*)(link_state + (size_t)i * DIM);
    #pragma unroll
    for (int c = 0; c < 8; ++c) {
        float4 v = { h[4*c], h[4*c+1], h[4*c+2], h[4*c+3] };
        ho[c] = v;
    }
}

// ---------- readout MLP: 32 -> 256 (selu) -> 256 (selu) -> 1 ----------
__global__ __launch_bounds__(256) void readout_kernel(
    const float* __restrict__ path_state,
    const float* __restrict__ R1, const float* __restrict__ Rb1,
    const float* __restrict__ R2, const float* __restrict__ Rb2,
    const float* __restrict__ R3, const float* __restrict__ Rb3,
    float* __restrict__ out)
{
    const int PB  = 32;
    const int STR = 260;                 // h1 row stride (floats)
    __shared__ float h0s[PB * DIM];
    __shared__ float h1s[PB * STR];
    __shared__ float outAcc[PB];
    int t  = threadIdx.x;
    int p0 = blockIdx.x * PB;

    for (int i = t; i < PB * DIM; i += 256)
        h0s[i] = path_state[(size_t)p0 * DIM + i];
    if (t < PB) outAcc[t] = 0.0f;
    __syncthreads();

    {
        int j = t;
        float r1[DIM];
        #pragma unroll
        for (int k = 0; k < DIM; ++k) r1[k] = R1[k * 256 + j];
        float bj = Rb1[j];
        for (int p = 0; p < PB; ++p) {
            float s = bj;
            #pragma unroll
            for (int k = 0; k < DIM; ++k) s += h0s[p * DIM + k] * r1[k];
            h1s[p * STR + j] = seluf(s);
        }
    }
    __syncthreads();

    int tj = t & 31, tp = t >> 5;
    int j0 = tj * 8, pp0 = tp * 4;
    float acc[4][8];
    #pragma unroll
    for (int pi = 0; pi < 4; ++pi)
        #pragma unroll
        for (int ji = 0; ji < 8; ++ji) acc[pi][ji] = Rb2[j0 + ji];

    for (int k = 0; k < 256; k += 4) {
        float xv[4][4];
        #pragma unroll
        for (int pi = 0; pi < 4; ++pi) {
            float4 v = *(const float4*)&h1s[(pp0 + pi) * STR + k];
            xv[pi][0] = v.x; xv[pi][1] = v.y; xv[pi][2] = v.z; xv[pi][3] = v.w;
        }
        #pragma unroll
        for (int kk = 0; kk < 4; ++kk) {
            float wv[8];
            #pragma unroll
            for (int ji = 0; ji < 8; ++ji) wv[ji] = R2[(k + kk) * 256 + j0 + ji];
            #pragma unroll
            for (int pi = 0; pi < 4; ++pi)
                #pragma unroll
                for (int ji = 0; ji < 8; ++ji)
                    acc[pi][ji] += xv[pi][kk] * wv[ji];
        }
    }

    float r3[8];
    #pragma unroll
    for (int ji = 0; ji < 8; ++ji) r3[ji] = R3[j0 + ji];
    #pragma unroll
    for (int pi = 0; pi < 4; ++pi) {
        float s = 0.0f;
        #pragma unroll
        for (int ji = 0; ji < 8; ++ji) s += seluf(acc[pi][ji]) * r3[ji];
        atomicAdd(&outAcc[pp0 + pi], s);
    }
    __syncthreads();
    if (t < PB) out[p0 + t] = outAcc[t] + Rb3[0];
}

extern "C" void kernel_launch(void* const* d_in, const int* in_sizes, int n_in,
                              void* d_out, int out_size, void* d_ws, size_t ws_size,
                              hipStream_t stream)
{
    const int*   links = (const int*)d_in[0];
    const float* cap = (const float*)d_in[3];
    const float* pol = (const float*)d_in[4];
    const float* wts = (const float*)d_in[5];
    const float* bw  = (const float*)d_in[6];
    const float* tos = (const float*)d_in[7];
    const float* pk  = (const float*)d_in[8];
    const float* avg = (const float*)d_in[9];
    const float* Wp  = (const float*)d_in[10];
    const float* Up  = (const float*)d_in[11];
    const float* bp  = (const float*)d_in[12];
    const float* Wl  = (const float*)d_in[13];
    const float* Ul  = (const float*)d_in[14];
    const float* bl  = (const float*)d_in[15];
    const float* R1  = (const float*)d_in[16];
    const float* Rb1 = (const float*)d_in[17];
    const float* R2  = (const float*)d_in[18];
    const float* Rb2 = (const float*)d_in[19];
    const float* R3  = (const float*)d_in[20];
    const float* Rb3 = (const float*)d_in[21];

    // workspace layout (256B aligned chunks), ~85 MB total
    char* w = (char*)d_ws;
    size_t off = 0;
    auto alloc = [&](size_t bytes) {
        char* p = w + off;
        off += (bytes + 255) & ~(size_t)255;
        return p;
    };
    float* path_state = (float*)alloc((size_t)NP * DIM * 4);        // 12.8 MB
    float* link_state = (float*)alloc((size_t)NLINKS * DIM * 4);    // 1.28 MB
    float* msg        = (float*)alloc((size_t)NLINKS * DIM * 4);    // 1.28 MB
    float* xg         = (float*)alloc((size_t)NLINKS * 96 * 4);     // 3.84 MB
    float* m          = (float*)alloc((size_t)E_TOT * DIM * 4);     // 64 MB
    int*   cnt        = (int*)alloc((size_t)NLINKS * 4);
    int*   row_start  = (int*)alloc((size_t)(NLINKS + 1) * 4);
    int*   cursor     = (int*)alloc((size_t)NLINKS * 4);
    int*   eid        = (int*)alloc((size_t)E_TOT * 4);             // 2 MB

    init_kernel<<<(NP + 255) / 256, 256, 0, stream>>>(cap, pol, wts, bw, tos, pk, avg,
                                                      link_state, path_state);
    // CSR (links constant across iterations -> build once per launch)
    hipMemsetAsync(cnt, 0, (size_t)NLINKS * 4, stream);
    csr_count  <<<(E_TOT + 255) / 256, 256, 0, stream>>>(links, cnt);
    csr_scan   <<<1, 256, 0, stream>>>(cnt, row_start, cursor);
    csr_scatter<<<(E_TOT + 255) / 256, 256, 0, stream>>>(links, cursor, eid);

    for (int it = 0; it < TITERS; ++it) {
        xg_kernel<<<(NLINKS + 255) / 256, 256, 0, stream>>>(link_state, Wp, bp, xg);
        if (it < TITERS - 1) {
            path_kernel<true><<<(NP + 255) / 256, 256, 0, stream>>>(links, xg, Up, bp,
                                                                    path_state, m);
            agg_kernel <<<(NLINKS * 64 + 255) / 256, 256, 0, stream>>>(row_start, eid, m, msg);
            link_kernel<<<(NLINKS + 255) / 256, 256, 0, stream>>>(Wl, Ul, bl, msg, link_state);
        } else {
            // last iteration: link update is dead (readout reads only path_state)
            path_kernel<false><<<(NP + 255) / 256, 256, 0, stream>>>(links, xg, Up, bp,
                                                                     path_state, m);
        }
    }
    readout_kernel<<<NP / 32, 256, 0, stream>>>(path_state, R1, Rb1, R2, Rb2, R3, Rb3,
                                                (float*)d_out);
}

// Round 10
// 2846.577 us; speedup vs baseline: 2.7440x; 2.2074x over previous
//
#include <hip/hip_runtime.h>
#include <hip/hip_bf16.h>

#define NP     100000   // n_paths
#define PLEN   5        // path length
#define NLINKS 10000    // n_links
#define DIM    32       // state dim
#define TITERS 8        // message passing iterations
#define E_TOT  (NP * PLEN)

// ---------- helpers ----------
__device__ __forceinline__ float fast_sigmoid(float v) {
    return 1.0f / (1.0f + __expf(-v));
}
__device__ __forceinline__ float fast_tanh(float v) {
    float e = __expf(-2.0f * fabsf(v));
    float t = (1.0f - e) / (1.0f + e);
    return v >= 0.0f ? t : -t;
}
__device__ __forceinline__ float seluf(float v) {
    const float sc = 1.0507009873554805f;
    const float al = 1.6732632423543772f;
    return v > 0.0f ? sc * v : sc * al * (__expf(v) - 1.0f);
}

// ---------- init ----------
__global__ __launch_bounds__(256) void init_kernel(
    const float* __restrict__ cap, const float* __restrict__ pol, const float* __restrict__ wts,
    const float* __restrict__ bw,  const float* __restrict__ tos,
    const float* __restrict__ pk,  const float* __restrict__ avg,
    float* __restrict__ link_state, float* __restrict__ path_state)
{
    int i = blockIdx.x * 256 + threadIdx.x;
    if (i < NLINKS) {
        float row[DIM];
        #pragma unroll
        for (int c = 0; c < DIM; ++c) row[c] = 0.0f;
        row[0] = cap[i]; row[1] = pol[i]; row[2] = wts[i];
        float4* o = (float4*)(link_state + (size_t)i * DIM);
        #pragma unroll
        for (int c = 0; c < 8; ++c) {
            float4 v = { row[4*c], row[4*c+1], row[4*c+2], row[4*c+3] };
            o[c] = v;
        }
    }
    if (i < NP) {
        float row[DIM];
        #pragma unroll
        for (int c = 0; c < DIM; ++c) row[c] = 0.0f;
        row[0] = bw[i]; row[1] = tos[i]; row[2] = pk[i]; row[3] = avg[i];
        float4* o = (float4*)(path_state + (size_t)i * DIM);
        #pragma unroll
        for (int c = 0; c < 8; ++c) {
            float4 v = { row[4*c], row[4*c+1], row[4*c+2], row[4*c+3] };
            o[c] = v;
        }
    }
}

// ---------- CSR build (links launch-invariant) ----------
__global__ __launch_bounds__(256) void csr_count(const int* __restrict__ links,
                                                 int* __restrict__ cnt)
{
    int e = blockIdx.x * 256 + threadIdx.x;
    if (e < E_TOT) atomicAdd(&cnt[links[e]], 1);
}

__global__ __launch_bounds__(256) void csr_scan(const int* __restrict__ cnt,
                                                int* __restrict__ row_start,
                                                int* __restrict__ cursor)
{
    __shared__ int s[256];
    int t = threadIdx.x;
    int carry = 0;
    for (int base = 0; base < NLINKS; base += 256) {
        int i = base + t;
        int v = (i < NLINKS) ? cnt[i] : 0;
        s[t] = v;
        __syncthreads();
        for (int off = 1; off < 256; off <<= 1) {
            int tv = (t >= off) ? s[t - off] : 0;
            __syncthreads();
            s[t] += tv;
            __syncthreads();
        }
        int excl = s[t] - v;
        if (i < NLINKS) { row_start[i] = carry + excl; cursor[i] = carry + excl; }
        int tot = s[255];
        __syncthreads();
        carry += tot;
    }
    if (t == 0) row_start[NLINKS] = carry;   // == E_TOT
}

__global__ __launch_bounds__(256) void csr_scatter(const int* __restrict__ links,
                                                   int* __restrict__ cursor,
                                                   int* __restrict__ eid)
{
    int e = blockIdx.x * 256 + threadIdx.x;
    if (e < E_TOT) {
        int slot = atomicAdd(&cursor[links[e]], 1);
        eid[slot] = e;
    }
}

// ---------- per-iteration: xg = link_state @ Wp + bp[0]  [NL,96] ----------
// Wp in LDS; unroll 2 on k-loop caps in-flight ds_reads (R9 lesson: full
// unroll hoists 256 ds_read results -> VGPR demand >> 256 -> scratch thrash).
__global__ __launch_bounds__(256, 1) void xg_kernel(const float* __restrict__ link_state,
                                                    const float* __restrict__ Wp,
                                                    const float* __restrict__ bp,
                                                    float* __restrict__ xg)
{
    __shared__ __align__(16) float wS[32 * 96];   // 12 KB
    __shared__ float bS[96];
    int t = threadIdx.x;
    {
        const float4* src = (const float4*)Wp;    // 768 float4
        float4* dst = (float4*)wS;
        #pragma unroll
        for (int i = 0; i < 3; ++i) dst[t + 256 * i] = src[t + 256 * i];
        if (t < 96) bS[t] = bp[t];                // input bias row
    }
    __syncthreads();
    int i = blockIdx.x * 256 + t;
    if (i >= NLINKS) return;
    float x[DIM];
    {
        const float4* xv = (const float4*)(link_state + (size_t)i * DIM);
        #pragma unroll
        for (int c = 0; c < 8; ++c) {
            float4 v = xv[c];
            x[4*c] = v.x; x[4*c+1] = v.y; x[4*c+2] = v.z; x[4*c+3] = v.w;
        }
    }
    #pragma unroll 1
    for (int g = 0; g < 3; ++g) {
        float acc[DIM];
        #pragma unroll
        for (int j = 0; j < DIM; ++j) acc[j] = bS[g * 32 + j];
        #pragma unroll 2
        for (int k = 0; k < DIM; ++k) {
            float xk = x[k];
            const float4* wv = (const float4*)&wS[k * 96 + g * 32];
            #pragma unroll
            for (int q = 0; q < 8; ++q) {
                float4 u = wv[q];
                acc[4*q]   += xk * u.x;
                acc[4*q+1] += xk * u.y;
                acc[4*q+2] += xk * u.z;
                acc[4*q+3] += xk * u.w;
            }
        }
        float4* o = (float4*)&xg[(size_t)i * 96 + g * 32];
        #pragma unroll
        for (int c = 0; c < 8; ++c) {
            float4 v = { acc[4*c], acc[4*c+1], acc[4*c+2], acc[4*c+3] };
            o[c] = v;
        }
    }
}

// ---------- path GRU over 5 hops; per-hop h -> m[E,32] (f32) ----------
// LDS-broadcast weights. Register-pressure control (the R7-R9 saga):
//  - gate order r -> n -> z: peak live = h(32)+acc(32)+r|hn(32) ~ 100
//  - #pragma unroll 2 on k-loops: <=16 float4 ds_reads in flight
//  - compile-time register indices only; block 256; loose bounds (256,1)
template <bool STORE_M>
__global__ __launch_bounds__(256, 1) void path_kernel(
    const int*   __restrict__ links,
    const float* __restrict__ xg,
    const float* __restrict__ Up, const float* __restrict__ bp,
    float* __restrict__ path_state,
    float* __restrict__ m)
{
    __shared__ __align__(16) float uS[32 * 96];   // 12 KB
    __shared__ float bS[96];                      // recurrent bias row
    int t = threadIdx.x;
    {
        const float4* src = (const float4*)Up;    // 768 float4
        float4* dst = (float4*)uS;
        #pragma unroll
        for (int i = 0; i < 3; ++i) dst[t + 256 * i] = src[t + 256 * i];
        if (t < 96) bS[t] = bp[96 + t];
    }
    __syncthreads();
    int p = blockIdx.x * 256 + t;
    if (p >= NP) return;

    float h[DIM];
    {
        const float4* hv = (const float4*)(path_state + (size_t)p * DIM);
        #pragma unroll
        for (int i = 0; i < 8; ++i) {
            float4 v = hv[i];
            h[4*i] = v.x; h[4*i+1] = v.y; h[4*i+2] = v.z; h[4*i+3] = v.w;
        }
    }
    #pragma unroll 1
    for (int l = 0; l < PLEN; ++l) {
        int link = links[p * PLEN + l];
        const float* xr = xg + (size_t)link * 96;
        float acc[DIM], rg[DIM];

        // ---- r gate: acc = xr[32..63] + b_r ; += h @ U[:,32:64] ----
        #pragma unroll
        for (int i = 0; i < 8; ++i) {
            float4 v = ((const float4*)(xr + 32))[i];
            acc[4*i]   = v.x + bS[32 + 4*i];
            acc[4*i+1] = v.y + bS[32 + 4*i+1];
            acc[4*i+2] = v.z + bS[32 + 4*i+2];
            acc[4*i+3] = v.w + bS[32 + 4*i+3];
        }
        #pragma unroll 2
        for (int k = 0; k < DIM; ++k) {
            float hk = h[k];
            const float4* u4 = (const float4*)&uS[k * 96 + 32];
            #pragma unroll
            for (int q = 0; q < 8; ++q) {
                float4 u = u4[q];
                acc[4*q]   += hk * u.x;
                acc[4*q+1] += hk * u.y;
                acc[4*q+2] += hk * u.z;
                acc[4*q+3] += hk * u.w;
            }
        }
        #pragma unroll
        for (int j = 0; j < DIM; ++j) rg[j] = fast_sigmoid(acc[j]);

        // ---- n gate recurrent: acc = b_n + h @ U[:,64:96]; hn -> rg ----
        #pragma unroll
        for (int j = 0; j < DIM; ++j) acc[j] = bS[64 + j];
        #pragma unroll 2
        for (int k = 0; k < DIM; ++k) {
            float hk = h[k];
            const float4* u4 = (const float4*)&uS[k * 96 + 64];
            #pragma unroll
            for (int q = 0; q < 8; ++q) {
                float4 u = u4[q];
                acc[4*q]   += hk * u.x;
                acc[4*q+1] += hk * u.y;
                acc[4*q+2] += hk * u.z;
                acc[4*q+3] += hk * u.w;
            }
        }
        #pragma unroll
        for (int i = 0; i < 8; ++i) {
            float4 v = ((const float4*)(xr + 64))[i];
            rg[4*i]   = fast_tanh(v.x + rg[4*i]   * acc[4*i]);
            rg[4*i+1] = fast_tanh(v.y + rg[4*i+1] * acc[4*i+1]);
            rg[4*i+2] = fast_tanh(v.z + rg[4*i+2] * acc[4*i+2]);
            rg[4*i+3] = fast_tanh(v.w + rg[4*i+3] * acc[4*i+3]);
        }

        // ---- z gate: acc = xr[0..31] + b_z ; += h @ U[:,0:32] ----
        #pragma unroll
        for (int i = 0; i < 8; ++i) {
            float4 v = ((const float4*)xr)[i];
            acc[4*i]   = v.x + bS[4*i];
            acc[4*i+1] = v.y + bS[4*i+1];
            acc[4*i+2] = v.z + bS[4*i+2];
            acc[4*i+3] = v.w + bS[4*i+3];
        }
        #pragma unroll 2
        for (int k = 0; k < DIM; ++k) {
            float hk = h[k];
            const float4* u4 = (const float4*)&uS[k * 96];
            #pragma unroll
            for (int q = 0; q < 8; ++q) {
                float4 u = u4[q];
                acc[4*q]   += hk * u.x;
                acc[4*q+1] += hk * u.y;
                acc[4*q+2] += hk * u.z;
                acc[4*q+3] += hk * u.w;
            }
        }
        #pragma unroll
        for (int j = 0; j < DIM; ++j) {
            float z = fast_sigmoid(acc[j]);
            h[j] = z * h[j] + (1.0f - z) * rg[j];   // rg holds hn
        }

        if (STORE_M) {
            float4* m4 = (float4*)(m + (size_t)(p * PLEN + l) * DIM);
            #pragma unroll
            for (int i = 0; i < 8; ++i) {
                float4 v = { h[4*i], h[4*i+1], h[4*i+2], h[4*i+3] };
                m4[i] = v;
            }
        }
    }
    float4* ho = (float4*)(path_state + (size_t)p * DIM);
    #pragma unroll
    for (int i = 0; i < 8; ++i) {
        float4 v = { h[4*i], h[4*i+1], h[4*i+2], h[4*i+3] };
        ho[i] = v;
    }
}

// ---------- CSR gather: msg[link] = sum over entries of m[e] ----------
__global__ __launch_bounds__(256) void agg_kernel(
    const int* __restrict__ row_start, const int* __restrict__ eid,
    const float* __restrict__ m, float* __restrict__ msg)
{
    int gid  = blockIdx.x * 256 + threadIdx.x;
    int link = gid >> 6;
    int lane = threadIdx.x & 63;
    if (link >= NLINKS) return;
    int s0 = row_start[link], s1 = row_start[link + 1];
    int half = lane >> 5, d = lane & 31;
    float v = 0.0f;
    for (int i = s0 + half; i < s1; i += 2) {
        int e = eid[i];
        v += m[(size_t)e * DIM + d];
    }
    v += __shfl_down(v, 32);
    if (lane < 32) msg[(size_t)link * DIM + d] = v;
}

// ---------- link GRU (Wl+Ul+biases in LDS; same pressure control) ----------
__global__ __launch_bounds__(256, 1) void link_kernel(
    const float* __restrict__ Wl, const float* __restrict__ Ul, const float* __restrict__ bl,
    const float* __restrict__ msg,
    float* __restrict__ link_state)
{
    __shared__ __align__(16) float wS[32 * 96];   // 12 KB
    __shared__ __align__(16) float uS[32 * 96];   // 12 KB
    __shared__ float bS[192];
    int t = threadIdx.x;
    {
        const float4* srcW = (const float4*)Wl;
        const float4* srcU = (const float4*)Ul;
        float4* dstW = (float4*)wS;
        float4* dstU = (float4*)uS;
        #pragma unroll
        for (int i = 0; i < 3; ++i) {
            dstW[t + 256 * i] = srcW[t + 256 * i];
            dstU[t + 256 * i] = srcU[t + 256 * i];
        }
        if (t < 192) bS[t] = bl[t];
    }
    __syncthreads();
    int i = blockIdx.x * 256 + t;
    if (i >= NLINKS) return;
    float h[DIM], x[DIM];
    {
        const float4* xv = (const float4*)(msg + (size_t)i * DIM);
        const float4* hv = (const float4*)(link_state + (size_t)i * DIM);
        #pragma unroll
        for (int c = 0; c < 8; ++c) {
            float4 a = xv[c];
            x[4*c] = a.x; x[4*c+1] = a.y; x[4*c+2] = a.z; x[4*c+3] = a.w;
            float4 b2 = hv[c];
            h[4*c] = b2.x; h[4*c+1] = b2.y; h[4*c+2] = b2.z; h[4*c+3] = b2.w;
        }
    }
    float acc[DIM], rg[DIM];

    // r
    #pragma unroll
    for (int j = 0; j < DIM; ++j) acc[j] = bS[32 + j] + bS[96 + 32 + j];
    #pragma unroll 2
    for (int k = 0; k < DIM; ++k) {
        float xk = x[k], hk = h[k];
        const float4* w4 = (const float4*)&wS[k * 96 + 32];
        const float4* u4 = (const float4*)&uS[k * 96 + 32];
        #pragma unroll
        for (int q = 0; q < 8; ++q) {
            float4 wv = w4[q], uv = u4[q];
            acc[4*q]   += xk * wv.x + hk * uv.x;
            acc[4*q+1] += xk * wv.y + hk * uv.y;
            acc[4*q+2] += xk * wv.z + hk * uv.z;
            acc[4*q+3] += xk * wv.w + hk * uv.w;
        }
    }
    #pragma unroll
    for (int j = 0; j < DIM; ++j) rg[j] = fast_sigmoid(acc[j]);

    // n: xn and hg separate (hn = tanh(xn + r*hg)); hn -> rg
    float accx[DIM];
    #pragma unroll
    for (int j = 0; j < DIM; ++j) { accx[j] = bS[64 + j]; acc[j] = bS[96 + 64 + j]; }
    #pragma unroll 2
    for (int k = 0; k < DIM; ++k) {
        float xk = x[k], hk = h[k];
        const float4* w4 = (const float4*)&wS[k * 96 + 64];
        const float4* u4 = (const float4*)&uS[k * 96 + 64];
        #pragma unroll
        for (int q = 0; q < 8; ++q) {
            float4 wv = w4[q], uv = u4[q];
            accx[4*q]   += xk * wv.x;  acc[4*q]   += hk * uv.x;
            accx[4*q+1] += xk * wv.y;  acc[4*q+1] += hk * uv.y;
            accx[4*q+2] += xk * wv.z;  acc[4*q+2] += hk * uv.z;
            accx[4*q+3] += xk * wv.w;  acc[4*q+3] += hk * uv.w;
        }
    }
    #pragma unroll
    for (int j = 0; j < DIM; ++j) rg[j] = fast_tanh(accx[j] + rg[j] * acc[j]);

    // z
    #pragma unroll
    for (int j = 0; j < DIM; ++j) acc[j] = bS[j] + bS[96 + j];
    #pragma unroll 2
    for (int k = 0; k < DIM; ++k) {
        float xk = x[k], hk = h[k];
        const float4* w4 = (const float4*)&wS[k * 96];
        const float4* u4 = (const float4*)&uS[k * 96];
        #pragma unroll
        for (int q = 0; q < 8; ++q) {
            float4 wv = w4[q], uv = u4[q];
            acc[4*q]   += xk * wv.x + hk * uv.x;
            acc[4*q+1] += xk * wv.y + hk * uv.y;
            acc[4*q+2] += xk * wv.z + hk * uv.z;
            acc[4*q+3] += xk * wv.w + hk * uv.w;
        }
    }
    #pragma unroll
    for (int j = 0; j < DIM; ++j) {
        float z = fast_sigmoid(acc[j]);
        h[j] = z * h[j] + (1.0f - z) * rg[j];
    }

    float4* ho = (float4*)(link_state + (size_t)i * DIM);
    #pragma unroll
    for (int c = 0; c < 8; ++c) {
        float4 v = { h[4*c], h[4*c+1], h[4*c+2], h[4*c+3] };
        ho[c] = v;
    }
}

// ---------- readout MLP: 32 -> 256 (selu) -> 256 (selu) -> 1 ----------
__global__ __launch_bounds__(256) void readout_kernel(
    const float* __restrict__ path_state,
    const float* __restrict__ R1, const float* __restrict__ Rb1,
    const float* __restrict__ R2, const float* __restrict__ Rb2,
    const float* __restrict__ R3, const float* __restrict__ Rb3,
    float* __restrict__ out)
{
    const int PB  = 32;
    const int STR = 260;                 // h1 row stride (floats)
    __shared__ float h0s[PB * DIM];
    __shared__ float h1s[PB * STR];
    __shared__ float outAcc[PB];
    int t  = threadIdx.x;
    int p0 = blockIdx.x * PB;

    for (int i = t; i < PB * DIM; i += 256)
        h0s[i] = path_state[(size_t)p0 * DIM + i];
    if (t < PB) outAcc[t] = 0.0f;
    __syncthreads();

    {
        int j = t;
        float r1[DIM];
        #pragma unroll
        for (int k = 0; k < DIM; ++k) r1[k] = R1[k * 256 + j];
        float bj = Rb1[j];
        for (int p = 0; p < PB; ++p) {
            float s = bj;
            #pragma unroll
            for (int k = 0; k < DIM; ++k) s += h0s[p * DIM + k] * r1[k];
            h1s[p * STR + j] = seluf(s);
        }
    }
    __syncthreads();

    int tj = t & 31, tp = t >> 5;
    int j0 = tj * 8, pp0 = tp * 4;
    float acc[4][8];
    #pragma unroll
    for (int pi = 0; pi < 4; ++pi)
        #pragma unroll
        for (int ji = 0; ji < 8; ++ji) acc[pi][ji] = Rb2[j0 + ji];

    for (int k = 0; k < 256; k += 4) {
        float xv[4][4];
        #pragma unroll
        for (int pi = 0; pi < 4; ++pi) {
            float4 v = *(const float4*)&h1s[(pp0 + pi) * STR + k];
            xv[pi][0] = v.x; xv[pi][1] = v.y; xv[pi][2] = v.z; xv[pi][3] = v.w;
        }
        #pragma unroll
        for (int kk = 0; kk < 4; ++kk) {
            float wv[8];
            #pragma unroll
            for (int ji = 0; ji < 8; ++ji) wv[ji] = R2[(k + kk) * 256 + j0 + ji];
            #pragma unroll
            for (int pi = 0; pi < 4; ++pi)
                #pragma unroll
                for (int ji = 0; ji < 8; ++ji)
                    acc[pi][ji] += xv[pi][kk] * wv[ji];
        }
    }

    float r3[8];
    #pragma unroll
    for (int ji = 0; ji < 8; ++ji) r3[ji] = R3[j0 + ji];
    #pragma unroll
    for (int pi = 0; pi < 4; ++pi) {
        float s = 0.0f;
        #pragma unroll
        for (int ji = 0; ji < 8; ++ji) s += seluf(acc[pi][ji]) * r3[ji];
        atomicAdd(&outAcc[pp0 + pi], s);
    }
    __syncthreads();
    if (t < PB) out[p0 + t] = outAcc[t] + Rb3[0];
}

extern "C" void kernel_launch(void* const* d_in, const int* in_sizes, int n_in,
                              void* d_out, int out_size, void* d_ws, size_t ws_size,
                              hipStream_t stream)
{
    const int*   links = (const int*)d_in[0];
    const float* cap = (const float*)d_in[3];
    const float* pol = (const float*)d_in[4];
    const float* wts = (const float*)d_in[5];
    const float* bw  = (const float*)d_in[6];
    const float* tos = (const float*)d_in[7];
    const float* pk  = (const float*)d_in[8];
    const float* avg = (const float*)d_in[9];
    const float* Wp  = (const float*)d_in[10];
    const float* Up  = (const float*)d_in[11];
    const float* bp  = (const float*)d_in[12];
    const float* Wl  = (const float*)d_in[13];
    const float* Ul  = (const float*)d_in[14];
    const float* bl  = (const float*)d_in[15];
    const float* R1  = (const float*)d_in[16];
    const float* Rb1 = (const float*)d_in[17];
    const float* R2  = (const float*)d_in[18];
    const float* Rb2 = (const float*)d_in[19];
    const float* R3  = (const float*)d_in[20];
    const float* Rb3 = (const float*)d_in[21];

    // workspace layout (256B aligned chunks), ~85 MB total
    char* w = (char*)d_ws;
    size_t off = 0;
    auto alloc = [&](size_t bytes) {
        char* p = w + off;
        off += (bytes + 255) & ~(size_t)255;
        return p;
    };
    float* path_state = (float*)alloc((size_t)NP * DIM * 4);        // 12.8 MB
    float* link_state = (float*)alloc((size_t)NLINKS * DIM * 4);    // 1.28 MB
    float* msg        = (float*)alloc((size_t)NLINKS * DIM * 4);    // 1.28 MB
    float* xg         = (float*)alloc((size_t)NLINKS * 96 * 4);     // 3.84 MB
    float* m          = (float*)alloc((size_t)E_TOT * DIM * 4);     // 64 MB
    int*   cnt        = (int*)alloc((size_t)NLINKS * 4);
    int*   row_start  = (int*)alloc((size_t)(NLINKS + 1) * 4);
    int*   cursor     = (int*)alloc((size_t)NLINKS * 4);
    int*   eid        = (int*)alloc((size_t)E_TOT * 4);             // 2 MB

    init_kernel<<<(NP + 255) / 256, 256, 0, stream>>>(cap, pol, wts, bw, tos, pk, avg,
                                                      link_state, path_state);
    // CSR (links constant across iterations -> build once per launch)
    hipMemsetAsync(cnt, 0, (size_t)NLINKS * 4, stream);
    csr_count  <<<(E_TOT + 255) / 256, 256, 0, stream>>>(links, cnt);
    csr_scan   <<<1, 256, 0, stream>>>(cnt, row_start, cursor);
    csr_scatter<<<(E_TOT + 255) / 256, 256, 0, stream>>>(links, cursor, eid);

    for (int it = 0; it < TITERS; ++it) {
        xg_kernel<<<(NLINKS + 255) / 256, 256, 0, stream>>>(link_state, Wp, bp, xg);
        if (it < TITERS - 1) {
            path_kernel<true><<<(NP + 255) / 256, 256, 0, stream>>>(links, xg, Up, bp,
                                                                    path_state, m);
            agg_kernel <<<(NLINKS * 64 + 255) / 256, 256, 0, stream>>>(row_start, eid, m, msg);
            link_kernel<<<(NLINKS + 255) / 256, 256, 0, stream>>>(Wl, Ul, bl, msg, link_state);
        } else {
            // last iteration: link update is dead (readout reads only path_state)
            path_kernel<false><<<(NP + 255) / 256, 256, 0, stream>>>(links, xg, Up, bp,
                                                                     path_state, m);
        }
    }
    readout_kernel<<<NP / 32, 256, 0, stream>>>(path_state, R1, Rb1, R2, Rb2, R3, Rb3,
                                                (float*)d_out);
}

// Round 11
// 1284.427 us; speedup vs baseline: 6.0812x; 2.2162x over previous
//
#include <hip/hip_runtime.h>
#include <hip/hip_bf16.h>

#define NP     100000   // n_paths
#define PLEN   5        // path length
#define NLINKS 10000    // n_links
#define DIM    32       // state dim
#define TITERS 8        // message passing iterations
#define E_TOT  (NP * PLEN)

using bf16x8 = __attribute__((ext_vector_type(8))) short;
using f32x4  = __attribute__((ext_vector_type(4))) float;
union FragCast { uint4 u; bf16x8 v; };

// ---------- helpers ----------
__device__ __forceinline__ float fast_sigmoid(float v) {
    return 1.0f / (1.0f + __expf(-v));
}
__device__ __forceinline__ float fast_tanh(float v) {
    float e = __expf(-2.0f * fabsf(v));
    float t = (1.0f - e) / (1.0f + e);
    return v >= 0.0f ? t : -t;
}
__device__ __forceinline__ float seluf(float v) {
    const float sc = 1.0507009873554805f;
    const float al = 1.6732632423543772f;
    return v > 0.0f ? sc * v : sc * al * (__expf(v) - 1.0f);
}
__device__ __forceinline__ unsigned short f2bf(float f) {
    union { float f; unsigned u; } c; c.f = f;
    unsigned u = c.u;
    return (unsigned short)((u + 0x7fffu + ((u >> 16) & 1u)) >> 16);
}
__device__ __forceinline__ float bf2f(unsigned short b) {
    union { unsigned u; float f; } c; c.u = ((unsigned)b) << 16;
    return c.f;
}
// split 8 f32 (A-row chunk) into hi/lo bf16 fragments (element j = k offset j)
__device__ __forceinline__ void split_bf16(const float (&v)[8], bf16x8& hi, bf16x8& lo) {
    unsigned uh[4], ul[4];
    #pragma unroll
    for (int i = 0; i < 4; ++i) {
        unsigned short h0 = f2bf(v[2*i]),   h1 = f2bf(v[2*i+1]);
        float r0 = v[2*i] - bf2f(h0),       r1 = v[2*i+1] - bf2f(h1);
        unsigned short l0 = f2bf(r0),       l1 = f2bf(r1);
        uh[i] = (unsigned)h0 | ((unsigned)h1 << 16);
        ul[i] = (unsigned)l0 | ((unsigned)l1 << 16);
    }
    FragCast ch, cl;
    ch.u.x = uh[0]; ch.u.y = uh[1]; ch.u.z = uh[2]; ch.u.w = uh[3];
    cl.u.x = ul[0]; cl.u.y = ul[1]; cl.u.z = ul[2]; cl.u.w = ul[3];
    hi = ch.v; lo = cl.v;
}

// ---------- init ----------
__global__ __launch_bounds__(256) void init_kernel(
    const float* __restrict__ cap, const float* __restrict__ pol, const float* __restrict__ wts,
    const float* __restrict__ bw,  const float* __restrict__ tos,
    const float* __restrict__ pk,  const float* __restrict__ avg,
    float* __restrict__ link_state, float* __restrict__ path_state)
{
    int i = blockIdx.x * 256 + threadIdx.x;
    if (i < NLINKS) {
        float row[DIM];
        #pragma unroll
        for (int c = 0; c < DIM; ++c) row[c] = 0.0f;
        row[0] = cap[i]; row[1] = pol[i]; row[2] = wts[i];
        float4* o = (float4*)(link_state + (size_t)i * DIM);
        #pragma unroll
        for (int c = 0; c < 8; ++c) {
            float4 v = { row[4*c], row[4*c+1], row[4*c+2], row[4*c+3] };
            o[c] = v;
        }
    }
    if (i < NP) {
        float row[DIM];
        #pragma unroll
        for (int c = 0; c < DIM; ++c) row[c] = 0.0f;
        row[0] = bw[i]; row[1] = tos[i]; row[2] = pk[i]; row[3] = avg[i];
        float4* o = (float4*)(path_state + (size_t)i * DIM);
        #pragma unroll
        for (int c = 0; c < 8; ++c) {
            float4 v = { row[4*c], row[4*c+1], row[4*c+2], row[4*c+3] };
            o[c] = v;
        }
    }
}

// ---------- CSR build (links launch-invariant) ----------
__global__ __launch_bounds__(256) void csr_count(const int* __restrict__ links,
                                                 int* __restrict__ cnt)
{
    int e = blockIdx.x * 256 + threadIdx.x;
    if (e < E_TOT) atomicAdd(&cnt[links[e]], 1);
}

__global__ __launch_bounds__(256) void csr_scan(const int* __restrict__ cnt,
                                                int* __restrict__ row_start,
                                                int* __restrict__ cursor)
{
    __shared__ int s[256];
    int t = threadIdx.x;
    int carry = 0;
    for (int base = 0; base < NLINKS; base += 256) {
        int i = base + t;
        int v = (i < NLINKS) ? cnt[i] : 0;
        s[t] = v;
        __syncthreads();
        for (int off = 1; off < 256; off <<= 1) {
            int tv = (t >= off) ? s[t - off] : 0;
            __syncthreads();
            s[t] += tv;
            __syncthreads();
        }
        int excl = s[t] - v;
        if (i < NLINKS) { row_start[i] = carry + excl; cursor[i] = carry + excl; }
        int tot = s[255];
        __syncthreads();
        carry += tot;
    }
    if (t == 0) row_start[NLINKS] = carry;   // == E_TOT
}

// slot[e] = this entry's position in link-sorted order; path_kernel writes m
// directly at slot -> agg reads contiguous rows (no eid indirection).
__global__ __launch_bounds__(256) void csr_scatter(const int* __restrict__ links,
                                                   int* __restrict__ cursor,
                                                   int* __restrict__ slot)
{
    int e = blockIdx.x * 256 + threadIdx.x;
    if (e < E_TOT) slot[e] = atomicAdd(&cursor[links[e]], 1);
}

// ---------- once per launch: weights -> MFMA B-fragments (hi/lo bf16) ----------
// frag layout: [ver 0=Whi 1=Wlo 2=Uhi 3=Ulo][tile g 0..5][lane 0..63][j 0..7]
// B[k][n]: n = g*16 + (lane&15), k = (lane>>4)*8 + j   (mirror of verified A layout)
__global__ __launch_bounds__(256) void wprep_kernel(const float* __restrict__ Wp,
                                                    const float* __restrict__ Up,
                                                    unsigned short* __restrict__ wfr)
{
    int idx = blockIdx.x * 256 + threadIdx.x;
    if (idx >= 6 * 64 * 8) return;
    int j = idx & 7, lane = (idx >> 3) & 63, g = idx >> 9;
    int k = (lane >> 4) * 8 + j;
    int n = g * 16 + (lane & 15);
    float w = Wp[k * 96 + n];
    float u = Up[k * 96 + n];
    unsigned short whi = f2bf(w); unsigned short wlo = f2bf(w - bf2f(whi));
    unsigned short uhi = f2bf(u); unsigned short ulo = f2bf(u - bf2f(uhi));
    wfr[0 * 3072 + idx] = whi;
    wfr[1 * 3072 + idx] = wlo;
    wfr[2 * 3072 + idx] = uhi;
    wfr[3 * 3072 + idx] = ulo;
}

// ---------- per iteration: link_state -> hi/lo bf16 rows ----------
__global__ __launch_bounds__(256) void lsbf_kernel(const float* __restrict__ link_state,
                                                   unsigned short* __restrict__ ls_hi,
                                                   unsigned short* __restrict__ ls_lo)
{
    int idx = blockIdx.x * 256 + threadIdx.x;       // one uint (2 elems) per thread
    if (idx >= NLINKS * DIM / 2) return;
    float2 v = *(const float2*)(link_state + (size_t)idx * 2);
    unsigned short h0 = f2bf(v.x), h1 = f2bf(v.y);
    unsigned short l0 = f2bf(v.x - bf2f(h0)), l1 = f2bf(v.y - bf2f(h1));
    ((unsigned*)ls_hi)[idx] = (unsigned)h0 | ((unsigned)h1 << 16);
    ((unsigned*)ls_lo)[idx] = (unsigned)l0 | ((unsigned)l1 << 16);
}

// ---------- MFMA path GRU: wave = 16 paths, weights resident in VGPR frags ----
// pre_act = [x@W] + [h@U] (+biases); hi/lo 3-term MFMA reconstructs f32 to ~2^-16.
// C/D: col=lane&15, row=quad*4+reg. A: A[m=lane&15][k=quad*8+j]. No block barriers:
// per-wave-private LDS region for the per-hop C->A transpose.
template <bool STORE_M>
__global__ __launch_bounds__(256) void path_kernel(
    const int*   __restrict__ links,
    const unsigned short* __restrict__ wfr,
    const float* __restrict__ bp,
    const unsigned short* __restrict__ ls_hi,
    const unsigned short* __restrict__ ls_lo,
    const int*   __restrict__ slot,
    float* __restrict__ path_state,
    float* __restrict__ m)
{
    __shared__ __align__(16) float T4[4][16 * 36];   // stride 36: banks spread, 144B rows 16B-aligned
    int t = threadIdx.x;
    int wave = t >> 6, lane = t & 63;
    int l15 = lane & 15, quad = lane >> 4;
    int p0 = (blockIdx.x * 4 + wave) * 16;
    if (p0 >= NP) return;
    float* T = T4[wave];
    int p = p0 + l15;                                // this lane's A-row path

    // resident weight fragments (96 VGPRs)
    bf16x8 Wh[6], Wl[6], Uh[6], Ul[6];
    {
        const uint4* base = (const uint4*)wfr;       // entry = 16B
        #pragma unroll
        for (int g = 0; g < 6; ++g) {
            FragCast a;
            a.u = base[0 * 384 + g * 64 + lane]; Wh[g] = a.v;
            a.u = base[1 * 384 + g * 64 + lane]; Wl[g] = a.v;
            a.u = base[2 * 384 + g * 64 + lane]; Uh[g] = a.v;
            a.u = base[3 * 384 + g * 64 + lane]; Ul[g] = a.v;
        }
    }
    // per-lane biases (col = hf*16 + l15)
    float bz[2], br[2], bnx[2], bnh[2];
    #pragma unroll
    for (int hf = 0; hf < 2; ++hf) {
        int c = hf * 16 + l15;
        bz[hf]  = bp[c]      + bp[96 + c];
        br[hf]  = bp[32 + c] + bp[96 + 32 + c];
        bnx[hf] = bp[64 + c];
        bnh[hf] = bp[96 + 64 + c];
    }

    // initial h: A-row chunk + C-layout copy via LDS
    float hA[8];
    {
        const float4* src = (const float4*)(path_state + (size_t)p * DIM + quad * 8);
        float4 v0 = src[0], v1 = src[1];
        hA[0]=v0.x; hA[1]=v0.y; hA[2]=v0.z; hA[3]=v0.w;
        hA[4]=v1.x; hA[5]=v1.y; hA[6]=v1.z; hA[7]=v1.w;
    }
    #pragma unroll
    for (int j = 0; j < 8; ++j) T[l15 * 36 + quad * 8 + j] = hA[j];
    __asm__ volatile("s_waitcnt lgkmcnt(0)" ::: "memory");
    float hC[2][4];
    #pragma unroll
    for (int hf = 0; hf < 2; ++hf)
        #pragma unroll
        for (int rg = 0; rg < 4; ++rg)
            hC[hf][rg] = T[(quad * 4 + rg) * 36 + hf * 16 + l15];

    bf16x8 ah, al;
    split_bf16(hA, ah, al);

    #pragma unroll 1
    for (int l = 0; l < PLEN; ++l) {
        int link = links[p * PLEN + l];
        FragCast cxh, cxl;
        cxh.u = *(const uint4*)(ls_hi + (size_t)link * DIM + quad * 8);
        cxl.u = *(const uint4*)(ls_lo + (size_t)link * DIM + quad * 8);
        bf16x8 xh = cxh.v, xl = cxl.v;

        #pragma unroll
        for (int hf = 0; hf < 2; ++hf) {
            f32x4 az = {0.f,0.f,0.f,0.f}, ar = {0.f,0.f,0.f,0.f};
            f32x4 axn = {0.f,0.f,0.f,0.f}, ahg = {0.f,0.f,0.f,0.f};
            int gz = hf, gr = 2 + hf, gn = 4 + hf;
            // z: x@Wz + h@Uz
            az = __builtin_amdgcn_mfma_f32_16x16x32_bf16(xh, Wh[gz], az, 0, 0, 0);
            az = __builtin_amdgcn_mfma_f32_16x16x32_bf16(xh, Wl[gz], az, 0, 0, 0);
            az = __builtin_amdgcn_mfma_f32_16x16x32_bf16(xl, Wh[gz], az, 0, 0, 0);
            az = __builtin_amdgcn_mfma_f32_16x16x32_bf16(ah, Uh[gz], az, 0, 0, 0);
            az = __builtin_amdgcn_mfma_f32_16x16x32_bf16(ah, Ul[gz], az, 0, 0, 0);
            az = __builtin_amdgcn_mfma_f32_16x16x32_bf16(al, Uh[gz], az, 0, 0, 0);
            // r
            ar = __builtin_amdgcn_mfma_f32_16x16x32_bf16(xh, Wh[gr], ar, 0, 0, 0);
            ar = __builtin_amdgcn_mfma_f32_16x16x32_bf16(xh, Wl[gr], ar, 0, 0, 0);
            ar = __builtin_amdgcn_mfma_f32_16x16x32_bf16(xl, Wh[gr], ar, 0, 0, 0);
            ar = __builtin_amdgcn_mfma_f32_16x16x32_bf16(ah, Uh[gr], ar, 0, 0, 0);
            ar = __builtin_amdgcn_mfma_f32_16x16x32_bf16(ah, Ul[gr], ar, 0, 0, 0);
            ar = __builtin_amdgcn_mfma_f32_16x16x32_bf16(al, Uh[gr], ar, 0, 0, 0);
            // n: xn and hg separate (reset_after)
            axn = __builtin_amdgcn_mfma_f32_16x16x32_bf16(xh, Wh[gn], axn, 0, 0, 0);
            axn = __builtin_amdgcn_mfma_f32_16x16x32_bf16(xh, Wl[gn], axn, 0, 0, 0);
            axn = __builtin_amdgcn_mfma_f32_16x16x32_bf16(xl, Wh[gn], axn, 0, 0, 0);
            ahg = __builtin_amdgcn_mfma_f32_16x16x32_bf16(ah, Uh[gn], ahg, 0, 0, 0);
            ahg = __builtin_amdgcn_mfma_f32_16x16x32_bf16(ah, Ul[gn], ahg, 0, 0, 0);
            ahg = __builtin_amdgcn_mfma_f32_16x16x32_bf16(al, Uh[gn], ahg, 0, 0, 0);
            #pragma unroll
            for (int rg = 0; rg < 4; ++rg) {
                float z  = fast_sigmoid(az[rg] + bz[hf]);
                float r  = fast_sigmoid(ar[rg] + br[hf]);
                float hn = fast_tanh(axn[rg] + bnx[hf] + r * (ahg[rg] + bnh[hf]));
                hC[hf][rg] = z * hC[hf][rg] + (1.0f - z) * hn;
            }
        }

        // C-layout -> A-row chunk via wave-private LDS
        __asm__ volatile("s_waitcnt lgkmcnt(0)" ::: "memory");
        #pragma unroll
        for (int hf = 0; hf < 2; ++hf)
            #pragma unroll
            for (int rg = 0; rg < 4; ++rg)
                T[(quad * 4 + rg) * 36 + hf * 16 + l15] = hC[hf][rg];
        __asm__ volatile("s_waitcnt lgkmcnt(0)" ::: "memory");
        {
            const float4* rd = (const float4*)(T + l15 * 36 + quad * 8);
            float4 v0 = rd[0], v1 = rd[1];
            hA[0]=v0.x; hA[1]=v0.y; hA[2]=v0.z; hA[3]=v0.w;
            hA[4]=v1.x; hA[5]=v1.y; hA[6]=v1.z; hA[7]=v1.w;
        }
        if (STORE_M) {
            int s = slot[p * PLEN + l];
            float4* dst = (float4*)(m + (size_t)s * DIM + quad * 8);
            float4 v0 = { hA[0], hA[1], hA[2], hA[3] };
            float4 v1 = { hA[4], hA[5], hA[6], hA[7] };
            dst[0] = v0; dst[1] = v1;
        }
        if (l < PLEN - 1) split_bf16(hA, ah, al);
    }
    float4* ho = (float4*)(path_state + (size_t)p * DIM + quad * 8);
    float4 v0 = { hA[0], hA[1], hA[2], hA[3] };
    float4 v1 = { hA[4], hA[5], hA[6], hA[7] };
    ho[0] = v0; ho[1] = v1;
}

// ---------- CSR gather (contiguous rows, slot-ordered m) ----------
__global__ __launch_bounds__(256) void agg_kernel(
    const int* __restrict__ row_start,
    const float* __restrict__ m, float* __restrict__ msg)
{
    int gid  = blockIdx.x * 256 + threadIdx.x;
    int link = gid >> 6;
    int lane = threadIdx.x & 63;
    if (link >= NLINKS) return;
    int s0 = row_start[link], s1 = row_start[link + 1];
    int half = lane >> 5, d = lane & 31;
    float v = 0.0f;
    for (int i = s0 + half; i < s1; i += 2)
        v += m[(size_t)i * DIM + d];
    v += __shfl_down(v, 32);
    if (lane < 32) msg[(size_t)link * DIM + d] = v;
}

// ---------- link GRU (R10 working version, unchanged) ----------
__global__ __launch_bounds__(256, 1) void link_kernel(
    const float* __restrict__ Wl, const float* __restrict__ Ul, const float* __restrict__ bl,
    const float* __restrict__ msg,
    float* __restrict__ link_state)
{
    __shared__ __align__(16) float wS[32 * 96];
    __shared__ __align__(16) float uS[32 * 96];
    __shared__ float bS[192];
    int t = threadIdx.x;
    {
        const float4* srcW = (const float4*)Wl;
        const float4* srcU = (const float4*)Ul;
        float4* dstW = (float4*)wS;
        float4* dstU = (float4*)uS;
        #pragma unroll
        for (int i = 0; i < 3; ++i) {
            dstW[t + 256 * i] = srcW[t + 256 * i];
            dstU[t + 256 * i] = srcU[t + 256 * i];
        }
        if (t < 192) bS[t] = bl[t];
    }
    __syncthreads();
    int i = blockIdx.x * 256 + t;
    if (i >= NLINKS) return;
    float h[DIM], x[DIM];
    {
        const float4* xv = (const float4*)(msg + (size_t)i * DIM);
        const float4* hv = (const float4*)(link_state + (size_t)i * DIM);
        #pragma unroll
        for (int c = 0; c < 8; ++c) {
            float4 a = xv[c];
            x[4*c] = a.x; x[4*c+1] = a.y; x[4*c+2] = a.z; x[4*c+3] = a.w;
            float4 b2 = hv[c];
            h[4*c] = b2.x; h[4*c+1] = b2.y; h[4*c+2] = b2.z; h[4*c+3] = b2.w;
        }
    }
    float acc[DIM], rg[DIM];

    // r
    #pragma unroll
    for (int j = 0; j < DIM; ++j) acc[j] = bS[32 + j] + bS[96 + 32 + j];
    #pragma unroll 2
    for (int k = 0; k < DIM; ++k) {
        float xk = x[k], hk = h[k];
        const float4* w4 = (const float4*)&wS[k * 96 + 32];
        const float4* u4 = (const float4*)&uS[k * 96 + 32];
        #pragma unroll
        for (int q = 0; q < 8; ++q) {
            float4 wv = w4[q], uv = u4[q];
            acc[4*q]   += xk * wv.x + hk * uv.x;
            acc[4*q+1] += xk * wv.y + hk * uv.y;
            acc[4*q+2] += xk * wv.z + hk * uv.z;
            acc[4*q+3] += xk * wv.w + hk * uv.w;
        }
    }
    #pragma unroll
    for (int j = 0; j < DIM; ++j) rg[j] = fast_sigmoid(acc[j]);

    // n
    float accx[DIM];
    #pragma unroll
    for (int j = 0; j < DIM; ++j) { accx[j] = bS[64 + j]; acc[j] = bS[96 + 64 + j]; }
    #pragma unroll 2
    for (int k = 0; k < DIM; ++k) {
        float xk = x[k], hk = h[k];
        const float4* w4 = (const float4*)&wS[k * 96 + 64];
        const float4* u4 = (const float4*)&uS[k * 96 + 64];
        #pragma unroll
        for (int q = 0; q < 8; ++q) {
            float4 wv = w4[q], uv = u4[q];
            accx[4*q]   += xk * wv.x;  acc[4*q]   += hk * uv.x;
            accx[4*q+1] += xk * wv.y;  acc[4*q+1] += hk * uv.y;
            accx[4*q+2] += xk * wv.z;  acc[4*q+2] += hk * uv.z;
            accx[4*q+3] += xk * wv.w;  acc[4*q+3] += hk * uv.w;
        }
    }
    #pragma unroll
    for (int j = 0; j < DIM; ++j) rg[j] = fast_tanh(accx[j] + rg[j] * acc[j]);

    // z
    #pragma unroll
    for (int j = 0; j < DIM; ++j) acc[j] = bS[j] + bS[96 + j];
    #pragma unroll 2
    for (int k = 0; k < DIM; ++k) {
        float xk = x[k], hk = h[k];
        const float4* w4 = (const float4*)&wS[k * 96];
        const float4* u4 = (const float4*)&uS[k * 96];
        #pragma unroll
        for (int q = 0; q < 8; ++q) {
            float4 wv = w4[q], uv = u4[q];
            acc[4*q]   += xk * wv.x + hk * uv.x;
            acc[4*q+1] += xk * wv.y + hk * uv.y;
            acc[4*q+2] += xk * wv.z + hk * uv.z;
            acc[4*q+3] += xk * wv.w + hk * uv.w;
        }
    }
    #pragma unroll
    for (int j = 0; j < DIM; ++j) {
        float z = fast_sigmoid(acc[j]);
        h[j] = z * h[j] + (1.0f - z) * rg[j];
    }

    float4* ho = (float4*)(link_state + (size_t)i * DIM);
    #pragma unroll
    for (int c = 0; c < 8; ++c) {
        float4 v = { h[4*c], h[4*c+1], h[4*c+2], h[4*c+3] };
        ho[c] = v;
    }
}

// ---------- readout MLP: 32 -> 256 (selu) -> 256 (selu) -> 1 ----------
__global__ __launch_bounds__(256) void readout_kernel(
    const float* __restrict__ path_state,
    const float* __restrict__ R1, const float* __restrict__ Rb1,
    const float* __restrict__ R2, const float* __restrict__ Rb2,
    const float* __restrict__ R3, const float* __restrict__ Rb3,
    float* __restrict__ out)
{
    const int PB  = 32;
    const int STR = 260;
    __shared__ float h0s[PB * DIM];
    __shared__ float h1s[PB * STR];
    __shared__ float outAcc[PB];
    int t  = threadIdx.x;
    int p0 = blockIdx.x * PB;

    for (int i = t; i < PB * DIM; i += 256)
        h0s[i] = path_state[(size_t)p0 * DIM + i];
    if (t < PB) outAcc[t] = 0.0f;
    __syncthreads();

    {
        int j = t;
        float r1[DIM];
        #pragma unroll
        for (int k = 0; k < DIM; ++k) r1[k] = R1[k * 256 + j];
        float bj = Rb1[j];
        for (int p = 0; p < PB; ++p) {
            float s = bj;
            #pragma unroll
            for (int k = 0; k < DIM; ++k) s += h0s[p * DIM + k] * r1[k];
            h1s[p * STR + j] = seluf(s);
        }
    }
    __syncthreads();

    int tj = t & 31, tp = t >> 5;
    int j0 = tj * 8, pp0 = tp * 4;
    float acc[4][8];
    #pragma unroll
    for (int pi = 0; pi < 4; ++pi)
        #pragma unroll
        for (int ji = 0; ji < 8; ++ji) acc[pi][ji] = Rb2[j0 + ji];

    for (int k = 0; k < 256; k += 4) {
        float xv[4][4];
        #pragma unroll
        for (int pi = 0; pi < 4; ++pi) {
            float4 v = *(const float4*)&h1s[(pp0 + pi) * STR + k];
            xv[pi][0] = v.x; xv[pi][1] = v.y; xv[pi][2] = v.z; xv[pi][3] = v.w;
        }
        #pragma unroll
        for (int kk = 0; kk < 4; ++kk) {
            float wv[8];
            #pragma unroll
            for (int ji = 0; ji < 8; ++ji) wv[ji] = R2[(k + kk) * 256 + j0 + ji];
            #pragma unroll
            for (int pi = 0; pi < 4; ++pi)
                #pragma unroll
                for (int ji = 0; ji < 8; ++ji)
                    acc[pi][ji] += xv[pi][kk] * wv[ji];
        }
    }

    float r3[8];
    #pragma unroll
    for (int ji = 0; ji < 8; ++ji) r3[ji] = R3[j0 + ji];
    #pragma unroll
    for (int pi = 0; pi < 4; ++pi) {
        float s = 0.0f;
        #pragma unroll
        for (int ji = 0; ji < 8; ++ji) s += seluf(acc[pi][ji]) * r3[ji];
        atomicAdd(&outAcc[pp0 + pi], s);
    }
    __syncthreads();
    if (t < PB) out[p0 + t] = outAcc[t] + Rb3[0];
}

extern "C" void kernel_launch(void* const* d_in, const int* in_sizes, int n_in,
                              void* d_out, int out_size, void* d_ws, size_t ws_size,
                              hipStream_t stream)
{
    const int*   links = (const int*)d_in[0];
    const float* cap = (const float*)d_in[3];
    const float* pol = (const float*)d_in[4];
    const float* wts = (const float*)d_in[5];
    const float* bw  = (const float*)d_in[6];
    const float* tos = (const float*)d_in[7];
    const float* pk  = (const float*)d_in[8];
    const float* avg = (const float*)d_in[9];
    const float* Wp  = (const float*)d_in[10];
    const float* Up  = (const float*)d_in[11];
    const float* bp  = (const float*)d_in[12];
    const float* Wl  = (const float*)d_in[13];
    const float* Ul  = (const float*)d_in[14];
    const float* bl  = (const float*)d_in[15];
    const float* R1  = (const float*)d_in[16];
    const float* Rb1 = (const float*)d_in[17];
    const float* R2  = (const float*)d_in[18];
    const float* Rb2 = (const float*)d_in[19];
    const float* R3  = (const float*)d_in[20];
    const float* Rb3 = (const float*)d_in[21];

    char* w = (char*)d_ws;
    size_t off = 0;
    auto alloc = [&](size_t bytes) {
        char* p = w + off;
        off += (bytes + 255) & ~(size_t)255;
        return p;
    };
    float*          path_state = (float*)alloc((size_t)NP * DIM * 4);        // 12.8 MB
    float*          link_state = (float*)alloc((size_t)NLINKS * DIM * 4);    // 1.28 MB
    float*          msg        = (float*)alloc((size_t)NLINKS * DIM * 4);    // 1.28 MB
    float*          m          = (float*)alloc((size_t)E_TOT * DIM * 4);     // 64 MB
    unsigned short* ls_hi      = (unsigned short*)alloc((size_t)NLINKS * DIM * 2);
    unsigned short* ls_lo      = (unsigned short*)alloc((size_t)NLINKS * DIM * 2);
    unsigned short* wfr        = (unsigned short*)alloc(4 * 3072 * 2);
    int*            cnt        = (int*)alloc((size_t)NLINKS * 4);
    int*            row_start  = (int*)alloc((size_t)(NLINKS + 1) * 4);
    int*            cursor     = (int*)alloc((size_t)NLINKS * 4);
    int*            slot       = (int*)alloc((size_t)E_TOT * 4);             // 2 MB

    init_kernel<<<(NP + 255) / 256, 256, 0, stream>>>(cap, pol, wts, bw, tos, pk, avg,
                                                      link_state, path_state);
    hipMemsetAsync(cnt, 0, (size_t)NLINKS * 4, stream);
    csr_count  <<<(E_TOT + 255) / 256, 256, 0, stream>>>(links, cnt);
    csr_scan   <<<1, 256, 0, stream>>>(cnt, row_start, cursor);
    csr_scatter<<<(E_TOT + 255) / 256, 256, 0, stream>>>(links, cursor, slot);
    wprep_kernel<<<12, 256, 0, stream>>>(Wp, Up, wfr);

    const int PGRID = (NP / 16 + 3) / 4;   // 1563 blocks, 4 waves each, wave guard inside
    for (int it = 0; it < TITERS; ++it) {
        lsbf_kernel<<<(NLINKS * DIM / 2 + 255) / 256, 256, 0, stream>>>(link_state, ls_hi, ls_lo);
        if (it < TITERS - 1) {
            path_kernel<true><<<PGRID, 256, 0, stream>>>(links, wfr, bp, ls_hi, ls_lo,
                                                         slot, path_state, m);
            agg_kernel <<<(NLINKS * 64 + 255) / 256, 256, 0, stream>>>(row_start, m, msg);
            link_kernel<<<(NLINKS + 255) / 256, 256, 0, stream>>>(Wl, Ul, bl, msg, link_state);
        } else {
            path_kernel<false><<<PGRID, 256, 0, stream>>>(links, wfr, bp, ls_hi, ls_lo,
                                                          slot, path_state, m);
        }
    }
    readout_kernel<<<NP / 32, 256, 0, stream>>>(path_state, R1, Rb1, R2, Rb2, R3, Rb3,
                                                (float*)d_out);
}

// Round 12
// 1110.764 us; speedup vs baseline: 7.0320x; 1.1563x over previous
//
#include <hip/hip_runtime.h>
#include <hip/hip_bf16.h>

#define NP     100000   // n_paths
#define PLEN   5        // path length
#define NLINKS 10000    // n_links
#define DIM    32       // state dim
#define TITERS 8        // message passing iterations
#define E_TOT  (NP * PLEN)

using bf16x8 = __attribute__((ext_vector_type(8))) short;
using f32x4  = __attribute__((ext_vector_type(4))) float;
union FragCast { uint4 u; bf16x8 v; };

// ---------- helpers ----------
__device__ __forceinline__ float fast_sigmoid(float v) {
    return 1.0f / (1.0f + __expf(-v));
}
__device__ __forceinline__ float fast_tanh(float v) {
    float e = __expf(-2.0f * fabsf(v));
    float t = (1.0f - e) / (1.0f + e);
    return v >= 0.0f ? t : -t;
}
__device__ __forceinline__ float seluf(float v) {
    const float sc = 1.0507009873554805f;
    const float al = 1.6732632423543772f;
    return v > 0.0f ? sc * v : sc * al * (__expf(v) - 1.0f);
}
__device__ __forceinline__ unsigned short f2bf(float f) {
    union { float f; unsigned u; } c; c.f = f;
    unsigned u = c.u;
    return (unsigned short)((u + 0x7fffu + ((u >> 16) & 1u)) >> 16);
}
__device__ __forceinline__ float bf2f(unsigned short b) {
    union { unsigned u; float f; } c; c.u = ((unsigned)b) << 16;
    return c.f;
}
__device__ __forceinline__ void split_bf16(const float (&v)[8], bf16x8& hi, bf16x8& lo) {
    unsigned uh[4], ul[4];
    #pragma unroll
    for (int i = 0; i < 4; ++i) {
        unsigned short h0 = f2bf(v[2*i]),   h1 = f2bf(v[2*i+1]);
        float r0 = v[2*i] - bf2f(h0),       r1 = v[2*i+1] - bf2f(h1);
        unsigned short l0 = f2bf(r0),       l1 = f2bf(r1);
        uh[i] = (unsigned)h0 | ((unsigned)h1 << 16);
        ul[i] = (unsigned)l0 | ((unsigned)l1 << 16);
    }
    FragCast ch, cl;
    ch.u.x = uh[0]; ch.u.y = uh[1]; ch.u.z = uh[2]; ch.u.w = uh[3];
    cl.u.x = ul[0]; cl.u.y = ul[1]; cl.u.z = ul[2]; cl.u.w = ul[3];
    hi = ch.v; lo = cl.v;
}

// ---------- init (also writes hi/lo split of initial link_state) ----------
__global__ __launch_bounds__(256) void init_kernel(
    const float* __restrict__ cap, const float* __restrict__ pol, const float* __restrict__ wts,
    const float* __restrict__ bw,  const float* __restrict__ tos,
    const float* __restrict__ pk,  const float* __restrict__ avg,
    float* __restrict__ link_state, float* __restrict__ path_state,
    unsigned short* __restrict__ ls_hi, unsigned short* __restrict__ ls_lo)
{
    int i = blockIdx.x * 256 + threadIdx.x;
    if (i < NLINKS) {
        float row[DIM];
        #pragma unroll
        for (int c = 0; c < DIM; ++c) row[c] = 0.0f;
        row[0] = cap[i]; row[1] = pol[i]; row[2] = wts[i];
        float4* o = (float4*)(link_state + (size_t)i * DIM);
        #pragma unroll
        for (int c = 0; c < 8; ++c) {
            float4 v = { row[4*c], row[4*c+1], row[4*c+2], row[4*c+3] };
            o[c] = v;
        }
        unsigned ush[16], usl[16];
        #pragma unroll
        for (int c = 0; c < 16; ++c) {
            unsigned short h0 = f2bf(row[2*c]), h1 = f2bf(row[2*c+1]);
            unsigned short l0 = f2bf(row[2*c] - bf2f(h0));
            unsigned short l1 = f2bf(row[2*c+1] - bf2f(h1));
            ush[c] = (unsigned)h0 | ((unsigned)h1 << 16);
            usl[c] = (unsigned)l0 | ((unsigned)l1 << 16);
        }
        uint4* oh = (uint4*)(ls_hi + (size_t)i * DIM);
        uint4* ol = (uint4*)(ls_lo + (size_t)i * DIM);
        #pragma unroll
        for (int q = 0; q < 4; ++q) {
            uint4 vh = { ush[4*q], ush[4*q+1], ush[4*q+2], ush[4*q+3] };
            uint4 vl = { usl[4*q], usl[4*q+1], usl[4*q+2], usl[4*q+3] };
            oh[q] = vh; ol[q] = vl;
        }
    }
    if (i < NP) {
        float row[DIM];
        #pragma unroll
        for (int c = 0; c < DIM; ++c) row[c] = 0.0f;
        row[0] = bw[i]; row[1] = tos[i]; row[2] = pk[i]; row[3] = avg[i];
        float4* o = (float4*)(path_state + (size_t)i * DIM);
        #pragma unroll
        for (int c = 0; c < 8; ++c) {
            float4 v = { row[4*c], row[4*c+1], row[4*c+2], row[4*c+3] };
            o[c] = v;
        }
    }
}

// ---------- CSR build ----------
__global__ __launch_bounds__(256) void csr_count(const int* __restrict__ links,
                                                 int* __restrict__ cnt)
{
    int e = blockIdx.x * 256 + threadIdx.x;
    if (e < E_TOT) atomicAdd(&cnt[links[e]], 1);
}

__global__ __launch_bounds__(256) void csr_scan(const int* __restrict__ cnt,
                                                int* __restrict__ row_start,
                                                int* __restrict__ cursor)
{
    __shared__ int s[256];
    int t = threadIdx.x;
    int carry = 0;
    for (int base = 0; base < NLINKS; base += 256) {
        int i = base + t;
        int v = (i < NLINKS) ? cnt[i] : 0;
        s[t] = v;
        __syncthreads();
        for (int off = 1; off < 256; off <<= 1) {
            int tv = (t >= off) ? s[t - off] : 0;
            __syncthreads();
            s[t] += tv;
            __syncthreads();
        }
        int excl = s[t] - v;
        if (i < NLINKS) { row_start[i] = carry + excl; cursor[i] = carry + excl; }
        int tot = s[255];
        __syncthreads();
        carry += tot;
    }
    if (t == 0) row_start[NLINKS] = carry;
}

__global__ __launch_bounds__(256) void csr_scatter(const int* __restrict__ links,
                                                   int* __restrict__ cursor,
                                                   int* __restrict__ slot)
{
    int e = blockIdx.x * 256 + threadIdx.x;
    if (e < E_TOT) slot[e] = atomicAdd(&cursor[links[e]], 1);
}

// ---------- once per launch: path-GRU weights -> MFMA B-frags (hi/lo) ----------
__global__ __launch_bounds__(256) void wprep_kernel(const float* __restrict__ Wp,
                                                    const float* __restrict__ Up,
                                                    unsigned short* __restrict__ wfr)
{
    int idx = blockIdx.x * 256 + threadIdx.x;
    if (idx >= 6 * 64 * 8) return;
    int j = idx & 7, lane = (idx >> 3) & 63, g = idx >> 9;
    int k = (lane >> 4) * 8 + j;
    int n = g * 16 + (lane & 15);
    float w = Wp[k * 96 + n];
    float u = Up[k * 96 + n];
    unsigned short whi = f2bf(w); unsigned short wlo = f2bf(w - bf2f(whi));
    unsigned short uhi = f2bf(u); unsigned short ulo = f2bf(u - bf2f(uhi));
    wfr[0 * 3072 + idx] = whi;
    wfr[1 * 3072 + idx] = wlo;
    wfr[2 * 3072 + idx] = uhi;
    wfr[3 * 3072 + idx] = ulo;
}

// ---------- once per launch: readout R1/R2 -> MFMA B-frags (hi/lo) ----------
// layout (shorts): [r1h 8192][r1l 8192][r2h 65536][r2l 65536]
__global__ __launch_bounds__(256) void rprep_kernel(const float* __restrict__ R1,
                                                    const float* __restrict__ R2,
                                                    unsigned short* __restrict__ rfr)
{
    int idx = blockIdx.x * 256 + threadIdx.x;
    if (idx >= 8192 + 65536) return;
    if (idx < 8192) {
        int j = idx & 7, lane = (idx >> 3) & 63, g = idx >> 9;   // g 0..15
        int k = (lane >> 4) * 8 + j;                              // 0..31
        int n = g * 16 + (lane & 15);
        float v = R1[k * 256 + n];
        unsigned short hi = f2bf(v);
        rfr[idx] = hi;
        rfr[8192 + idx] = f2bf(v - bf2f(hi));
    } else {
        int idx2 = idx - 8192;
        int j = idx2 & 7, lane = (idx2 >> 3) & 63, tile = idx2 >> 9; // tile 0..127
        int c = tile >> 4, g = tile & 15;
        int k = c * 32 + (lane >> 4) * 8 + j;
        int n = g * 16 + (lane & 15);
        float v = R2[k * 256 + n];
        unsigned short hi = f2bf(v);
        rfr[16384 + idx2] = hi;
        rfr[16384 + 65536 + idx2] = f2bf(v - bf2f(hi));
    }
}

// ---------- MFMA path GRU (R11-verified layouts) + full unroll + prefetch ----
template <bool STORE_M>
__global__ __launch_bounds__(256) void path_kernel(
    const int*   __restrict__ links,
    const unsigned short* __restrict__ wfr,
    const float* __restrict__ bp,
    const unsigned short* __restrict__ ls_hi,
    const unsigned short* __restrict__ ls_lo,
    const int*   __restrict__ slot,
    float* __restrict__ path_state,
    float* __restrict__ m)
{
    __shared__ __align__(16) float T4[4][16 * 36];
    int t = threadIdx.x;
    int wave = t >> 6, lane = t & 63;
    int l15 = lane & 15, quad = lane >> 4;
    int p0 = (blockIdx.x * 4 + wave) * 16;
    if (p0 >= NP) return;
    float* T = T4[wave];
    int p = p0 + l15;

    // prefetch: links, x-fragments (all hops known upfront), slots
    int lk[PLEN];
    #pragma unroll
    for (int l = 0; l < PLEN; ++l) lk[l] = links[p * PLEN + l];
    bf16x8 pxh[PLEN], pxl[PLEN];
    #pragma unroll
    for (int l = 0; l < PLEN; ++l) {
        FragCast ch, cl;
        ch.u = *(const uint4*)(ls_hi + (size_t)lk[l] * DIM + quad * 8);
        cl.u = *(const uint4*)(ls_lo + (size_t)lk[l] * DIM + quad * 8);
        pxh[l] = ch.v; pxl[l] = cl.v;
    }
    int sl[PLEN];
    if (STORE_M) {
        #pragma unroll
        for (int l = 0; l < PLEN; ++l) sl[l] = slot[p * PLEN + l];
    }

    // resident weight fragments (96 VGPRs)
    bf16x8 Wh[6], Wl[6], Uh[6], Ul[6];
    {
        const uint4* base = (const uint4*)wfr;
        #pragma unroll
        for (int g = 0; g < 6; ++g) {
            FragCast a;
            a.u = base[0 * 384 + g * 64 + lane]; Wh[g] = a.v;
            a.u = base[1 * 384 + g * 64 + lane]; Wl[g] = a.v;
            a.u = base[2 * 384 + g * 64 + lane]; Uh[g] = a.v;
            a.u = base[3 * 384 + g * 64 + lane]; Ul[g] = a.v;
        }
    }
    float bz[2], br[2], bnx[2], bnh[2];
    #pragma unroll
    for (int hf = 0; hf < 2; ++hf) {
        int c = hf * 16 + l15;
        bz[hf]  = bp[c]      + bp[96 + c];
        br[hf]  = bp[32 + c] + bp[96 + 32 + c];
        bnx[hf] = bp[64 + c];
        bnh[hf] = bp[96 + 64 + c];
    }

    float hA[8];
    {
        const float4* src = (const float4*)(path_state + (size_t)p * DIM + quad * 8);
        float4 v0 = src[0], v1 = src[1];
        hA[0]=v0.x; hA[1]=v0.y; hA[2]=v0.z; hA[3]=v0.w;
        hA[4]=v1.x; hA[5]=v1.y; hA[6]=v1.z; hA[7]=v1.w;
    }
    #pragma unroll
    for (int j = 0; j < 8; ++j) T[l15 * 36 + quad * 8 + j] = hA[j];
    __asm__ volatile("s_waitcnt lgkmcnt(0)" ::: "memory");
    float hC[2][4];
    #pragma unroll
    for (int hf = 0; hf < 2; ++hf)
        #pragma unroll
        for (int rg = 0; rg < 4; ++rg)
            hC[hf][rg] = T[(quad * 4 + rg) * 36 + hf * 16 + l15];

    bf16x8 ah, al;
    split_bf16(hA, ah, al);

    #pragma unroll
    for (int l = 0; l < PLEN; ++l) {
        bf16x8 xh = pxh[l], xl = pxl[l];
        #pragma unroll
        for (int hf = 0; hf < 2; ++hf) {
            f32x4 az = {0.f,0.f,0.f,0.f}, ar = {0.f,0.f,0.f,0.f};
            f32x4 axn = {0.f,0.f,0.f,0.f}, ahg = {0.f,0.f,0.f,0.f};
            int gz = hf, gr = 2 + hf, gn = 4 + hf;
            az = __builtin_amdgcn_mfma_f32_16x16x32_bf16(xh, Wh[gz], az, 0, 0, 0);
            az = __builtin_amdgcn_mfma_f32_16x16x32_bf16(xh, Wl[gz], az, 0, 0, 0);
            az = __builtin_amdgcn_mfma_f32_16x16x32_bf16(xl, Wh[gz], az, 0, 0, 0);
            az = __builtin_amdgcn_mfma_f32_16x16x32_bf16(ah, Uh[gz], az, 0, 0, 0);
            az = __builtin_amdgcn_mfma_f32_16x16x32_bf16(ah, Ul[gz], az, 0, 0, 0);
            az = __builtin_amdgcn_mfma_f32_16x16x32_bf16(al, Uh[gz], az, 0, 0, 0);
            ar = __builtin_amdgcn_mfma_f32_16x16x32_bf16(xh, Wh[gr], ar, 0, 0, 0);
            ar = __builtin_amdgcn_mfma_f32_16x16x32_bf16(xh, Wl[gr], ar, 0, 0, 0);
            ar = __builtin_amdgcn_mfma_f32_16x16x32_bf16(xl, Wh[gr], ar, 0, 0, 0);
            ar = __builtin_amdgcn_mfma_f32_16x16x32_bf16(ah, Uh[gr], ar, 0, 0, 0);
            ar = __builtin_amdgcn_mfma_f32_16x16x32_bf16(ah, Ul[gr], ar, 0, 0, 0);
            ar = __builtin_amdgcn_mfma_f32_16x16x32_bf16(al, Uh[gr], ar, 0, 0, 0);
            axn = __builtin_amdgcn_mfma_f32_16x16x32_bf16(xh, Wh[gn], axn, 0, 0, 0);
            axn = __builtin_amdgcn_mfma_f32_16x16x32_bf16(xh, Wl[gn], axn, 0, 0, 0);
            axn = __builtin_amdgcn_mfma_f32_16x16x32_bf16(xl, Wh[gn], axn, 0, 0, 0);
            ahg = __builtin_amdgcn_mfma_f32_16x16x32_bf16(ah, Uh[gn], ahg, 0, 0, 0);
            ahg = __builtin_amdgcn_mfma_f32_16x16x32_bf16(ah, Ul[gn], ahg, 0, 0, 0);
            ahg = __builtin_amdgcn_mfma_f32_16x16x32_bf16(al, Uh[gn], ahg, 0, 0, 0);
            #pragma unroll
            for (int rg = 0; rg < 4; ++rg) {
                float z  = fast_sigmoid(az[rg] + bz[hf]);
                float r  = fast_sigmoid(ar[rg] + br[hf]);
                float hn = fast_tanh(axn[rg] + bnx[hf] + r * (ahg[rg] + bnh[hf]));
                hC[hf][rg] = z * hC[hf][rg] + (1.0f - z) * hn;
            }
        }

        __asm__ volatile("s_waitcnt lgkmcnt(0)" ::: "memory");
        #pragma unroll
        for (int hf = 0; hf < 2; ++hf)
            #pragma unroll
            for (int rg = 0; rg < 4; ++rg)
                T[(quad * 4 + rg) * 36 + hf * 16 + l15] = hC[hf][rg];
        __asm__ volatile("s_waitcnt lgkmcnt(0)" ::: "memory");
        {
            const float4* rd = (const float4*)(T + l15 * 36 + quad * 8);
            float4 v0 = rd[0], v1 = rd[1];
            hA[0]=v0.x; hA[1]=v0.y; hA[2]=v0.z; hA[3]=v0.w;
            hA[4]=v1.x; hA[5]=v1.y; hA[6]=v1.z; hA[7]=v1.w;
        }
        if (STORE_M) {
            float4* dst = (float4*)(m + (size_t)sl[l] * DIM + quad * 8);
            float4 v0 = { hA[0], hA[1], hA[2], hA[3] };
            float4 v1 = { hA[4], hA[5], hA[6], hA[7] };
            dst[0] = v0; dst[1] = v1;
        }
        if (l < PLEN - 1) split_bf16(hA, ah, al);
    }
    float4* ho = (float4*)(path_state + (size_t)p * DIM + quad * 8);
    float4 v0 = { hA[0], hA[1], hA[2], hA[3] };
    float4 v1 = { hA[4], hA[5], hA[6], hA[7] };
    ho[0] = v0; ho[1] = v1;
}

// ---------- CSR gather (contiguous rows) ----------
__global__ __launch_bounds__(256) void agg_kernel(
    const int* __restrict__ row_start,
    const float* __restrict__ m, float* __restrict__ msg)
{
    int gid  = blockIdx.x * 256 + threadIdx.x;
    int link = gid >> 6;
    int lane = threadIdx.x & 63;
    if (link >= NLINKS) return;
    int s0 = row_start[link], s1 = row_start[link + 1];
    int half = lane >> 5, d = lane & 31;
    float v = 0.0f;
    for (int i = s0 + half; i < s1; i += 2)
        v += m[(size_t)i * DIM + d];
    v += __shfl_down(v, 32);
    if (lane < 32) msg[(size_t)link * DIM + d] = v;
}

// ---------- link GRU (R10 structure) + fused hi/lo split store ----------
__global__ __launch_bounds__(256, 1) void link_kernel(
    const float* __restrict__ Wl, const float* __restrict__ Ul, const float* __restrict__ bl,
    const float* __restrict__ msg,
    float* __restrict__ link_state,
    unsigned short* __restrict__ ls_hi, unsigned short* __restrict__ ls_lo)
{
    __shared__ __align__(16) float wS[32 * 96];
    __shared__ __align__(16) float uS[32 * 96];
    __shared__ float bS[192];
    int t = threadIdx.x;
    {
        const float4* srcW = (const float4*)Wl;
        const float4* srcU = (const float4*)Ul;
        float4* dstW = (float4*)wS;
        float4* dstU = (float4*)uS;
        #pragma unroll
        for (int i = 0; i < 3; ++i) {
            dstW[t + 256 * i] = srcW[t + 256 * i];
            dstU[t + 256 * i] = srcU[t + 256 * i];
        }
        if (t < 192) bS[t] = bl[t];
    }
    __syncthreads();
    int i = blockIdx.x * 256 + t;
    if (i >= NLINKS) return;
    float h[DIM], x[DIM];
    {
        const float4* xv = (const float4*)(msg + (size_t)i * DIM);
        const float4* hv = (const float4*)(link_state + (size_t)i * DIM);
        #pragma unroll
        for (int c = 0; c < 8; ++c) {
            float4 a = xv[c];
            x[4*c] = a.x; x[4*c+1] = a.y; x[4*c+2] = a.z; x[4*c+3] = a.w;
            float4 b2 = hv[c];
            h[4*c] = b2.x; h[4*c+1] = b2.y; h[4*c+2] = b2.z; h[4*c+3] = b2.w;
        }
    }
    float acc[DIM], rg[DIM];

    // r
    #pragma unroll
    for (int j = 0; j < DIM; ++j) acc[j] = bS[32 + j] + bS[96 + 32 + j];
    #pragma unroll 2
    for (int k = 0; k < DIM; ++k) {
        float xk = x[k], hk = h[k];
        const float4* w4 = (const float4*)&wS[k * 96 + 32];
        const float4* u4 = (const float4*)&uS[k * 96 + 32];
        #pragma unroll
        for (int q = 0; q < 8; ++q) {
            float4 wv = w4[q], uv = u4[q];
            acc[4*q]   += xk * wv.x + hk * uv.x;
            acc[4*q+1] += xk * wv.y + hk * uv.y;
            acc[4*q+2] += xk * wv.z + hk * uv.z;
            acc[4*q+3] += xk * wv.w + hk * uv.w;
        }
    }
    #pragma unroll
    for (int j = 0; j < DIM; ++j) rg[j] = fast_sigmoid(acc[j]);

    // n
    float accx[DIM];
    #pragma unroll
    for (int j = 0; j < DIM; ++j) { accx[j] = bS[64 + j]; acc[j] = bS[96 + 64 + j]; }
    #pragma unroll 2
    for (int k = 0; k < DIM; ++k) {
        float xk = x[k], hk = h[k];
        const float4* w4 = (const float4*)&wS[k * 96 + 64];
        const float4* u4 = (const float4*)&uS[k * 96 + 64];
        #pragma unroll
        for (int q = 0; q < 8; ++q) {
            float4 wv = w4[q], uv = u4[q];
            accx[4*q]   += xk * wv.x;  acc[4*q]   += hk * uv.x;
            accx[4*q+1] += xk * wv.y;  acc[4*q+1] += hk * uv.y;
            accx[4*q+2] += xk * wv.z;  acc[4*q+2] += hk * uv.z;
            accx[4*q+3] += xk * wv.w;  acc[4*q+3] += hk * uv.w;
        }
    }
    #pragma unroll
    for (int j = 0; j < DIM; ++j) rg[j] = fast_tanh(accx[j] + rg[j] * acc[j]);

    // z
    #pragma unroll
    for (int j = 0; j < DIM; ++j) acc[j] = bS[j] + bS[96 + j];
    #pragma unroll 2
    for (int k = 0; k < DIM; ++k) {
        float xk = x[k], hk = h[k];
        const float4* w4 = (const float4*)&wS[k * 96];
        const float4* u4 = (const float4*)&uS[k * 96];
        #pragma unroll
        for (int q = 0; q < 8; ++q) {
            float4 wv = w4[q], uv = u4[q];
            acc[4*q]   += xk * wv.x + hk * uv.x;
            acc[4*q+1] += xk * wv.y + hk * uv.y;
            acc[4*q+2] += xk * wv.z + hk * uv.z;
            acc[4*q+3] += xk * wv.w + hk * uv.w;
        }
    }
    #pragma unroll
    for (int j = 0; j < DIM; ++j) {
        float z = fast_sigmoid(acc[j]);
        h[j] = z * h[j] + (1.0f - z) * rg[j];
    }

    float4* ho = (float4*)(link_state + (size_t)i * DIM);
    #pragma unroll
    for (int c = 0; c < 8; ++c) {
        float4 v = { h[4*c], h[4*c+1], h[4*c+2], h[4*c+3] };
        ho[c] = v;
    }
    // fused lsbf: hi/lo split of new link_state
    unsigned ush[16], usl[16];
    #pragma unroll
    for (int c = 0; c < 16; ++c) {
        unsigned short h0 = f2bf(h[2*c]), h1 = f2bf(h[2*c+1]);
        unsigned short l0 = f2bf(h[2*c] - bf2f(h0));
        unsigned short l1 = f2bf(h[2*c+1] - bf2f(h1));
        ush[c] = (unsigned)h0 | ((unsigned)h1 << 16);
        usl[c] = (unsigned)l0 | ((unsigned)l1 << 16);
    }
    uint4* oh = (uint4*)(ls_hi + (size_t)i * DIM);
    uint4* ol = (uint4*)(ls_lo + (size_t)i * DIM);
    #pragma unroll
    for (int q = 0; q < 4; ++q) {
        uint4 vh = { ush[4*q], ush[4*q+1], ush[4*q+2], ush[4*q+3] };
        uint4 vl = { usl[4*q], usl[4*q+1], usl[4*q+2], usl[4*q+3] };
        oh[q] = vh; ol[q] = vl;
    }
}

// ---------- MFMA readout: 32 -> 256 (selu) -> 256 (selu) -> @R3 ----------
// wave = 16 paths; block = 2 waves. hi/lo 3-term MFMA (validated in path_kernel).
// h1 wave-private LDS transpose, stride 260 f32 (2-way write, balanced b128 read).
__global__ __launch_bounds__(128, 1) void readout_kernel(
    const float* __restrict__ path_state,
    const unsigned short* __restrict__ rfr,
    const float* __restrict__ Rb1, const float* __restrict__ Rb2,
    const float* __restrict__ R3,  const float* __restrict__ Rb3,
    float* __restrict__ out)
{
    __shared__ __align__(16) float T2[2][16 * 260];   // 33.3 KB
    int t = threadIdx.x;
    int wave = t >> 6, lane = t & 63;
    int l15 = lane & 15, quad = lane >> 4;
    int p0 = (blockIdx.x * 2 + wave) * 16;
    if (p0 >= NP) return;
    float* T = T2[wave];
    int p = p0 + l15;

    const uint4* r1h = (const uint4*)rfr;             // 1024 uint4
    const uint4* r1l = r1h + 1024;
    const uint4* r2h = r1l + 1024;                    // 8192 uint4
    const uint4* r2l = r2h + 8192;

    // layer 1: h1 = selu(h0 @ R1 + Rb1)
    float h0[8];
    {
        const float4* src = (const float4*)(path_state + (size_t)p * DIM + quad * 8);
        float4 v0 = src[0], v1 = src[1];
        h0[0]=v0.x; h0[1]=v0.y; h0[2]=v0.z; h0[3]=v0.w;
        h0[4]=v1.x; h0[5]=v1.y; h0[6]=v1.z; h0[7]=v1.w;
    }
    bf16x8 a0h, a0l;
    split_bf16(h0, a0h, a0l);
    #pragma unroll 1
    for (int g = 0; g < 16; ++g) {
        FragCast bh, bl2;
        bh.u  = r1h[g * 64 + lane];
        bl2.u = r1l[g * 64 + lane];
        f32x4 c = {0.f,0.f,0.f,0.f};
        c = __builtin_amdgcn_mfma_f32_16x16x32_bf16(a0h, bh.v,  c, 0, 0, 0);
        c = __builtin_amdgcn_mfma_f32_16x16x32_bf16(a0h, bl2.v, c, 0, 0, 0);
        c = __builtin_amdgcn_mfma_f32_16x16x32_bf16(a0l, bh.v,  c, 0, 0, 0);
        float rb = Rb1[g * 16 + l15];
        #pragma unroll
        for (int rg = 0; rg < 4; ++rg)
            T[(quad * 4 + rg) * 260 + g * 16 + l15] = seluf(c[rg] + rb);
    }
    __asm__ volatile("s_waitcnt lgkmcnt(0)" ::: "memory");

    // h1 A-fragments (row = path = l15, k = c*32 + quad*8 + j)
    bf16x8 h1h[8], h1l[8];
    #pragma unroll
    for (int c = 0; c < 8; ++c) {
        float hv[8];
        const float4* rd = (const float4*)(T + l15 * 260 + c * 32 + quad * 8);
        float4 u0 = rd[0], u1 = rd[1];
        hv[0]=u0.x; hv[1]=u0.y; hv[2]=u0.z; hv[3]=u0.w;
        hv[4]=u1.x; hv[5]=u1.y; hv[6]=u1.z; hv[7]=u1.w;
        split_bf16(hv, h1h[c], h1l[c]);
    }

    // layer 2 + 3: s = selu(h1 @ R2 + Rb2) @ R3
    float s[4] = {0.f, 0.f, 0.f, 0.f};
    #pragma unroll 1
    for (int g = 0; g < 16; ++g) {
        f32x4 acc = {0.f,0.f,0.f,0.f};
        #pragma unroll
        for (int c = 0; c < 8; ++c) {
            FragCast bh, bl2;
            bh.u  = r2h[(c * 16 + g) * 64 + lane];
            bl2.u = r2l[(c * 16 + g) * 64 + lane];
            acc = __builtin_amdgcn_mfma_f32_16x16x32_bf16(h1h[c], bh.v,  acc, 0, 0, 0);
            acc = __builtin_amdgcn_mfma_f32_16x16x32_bf16(h1h[c], bl2.v, acc, 0, 0, 0);
            acc = __builtin_amdgcn_mfma_f32_16x16x32_bf16(h1l[c], bh.v,  acc, 0, 0, 0);
        }
        float rb  = Rb2[g * 16 + l15];
        float r3v = R3[g * 16 + l15];
        #pragma unroll
        for (int rg = 0; rg < 4; ++rg)
            s[rg] += seluf(acc[rg] + rb) * r3v;
    }
    // reduce over the 16 cols held across l15 (stays within quad)
    #pragma unroll
    for (int rg = 0; rg < 4; ++rg) {
        s[rg] += __shfl_xor(s[rg], 1);
        s[rg] += __shfl_xor(s[rg], 2);
        s[rg] += __shfl_xor(s[rg], 4);
        s[rg] += __shfl_xor(s[rg], 8);
    }
    if (l15 == 0) {
        float rb3 = Rb3[0];
        #pragma unroll
        for (int rg = 0; rg < 4; ++rg)
            out[p0 + quad * 4 + rg] = s[rg] + rb3;
    }
}

extern "C" void kernel_launch(void* const* d_in, const int* in_sizes, int n_in,
                              void* d_out, int out_size, void* d_ws, size_t ws_size,
                              hipStream_t stream)
{
    const int*   links = (const int*)d_in[0];
    const float* cap = (const float*)d_in[3];
    const float* pol = (const float*)d_in[4];
    const float* wts = (const float*)d_in[5];
    const float* bw  = (const float*)d_in[6];
    const float* tos = (const float*)d_in[7];
    const float* pk  = (const float*)d_in[8];
    const float* avg = (const float*)d_in[9];
    const float* Wp  = (const float*)d_in[10];
    const float* Up  = (const float*)d_in[11];
    const float* bp  = (const float*)d_in[12];
    const float* Wl  = (const float*)d_in[13];
    const float* Ul  = (const float*)d_in[14];
    const float* bl  = (const float*)d_in[15];
    const float* R1  = (const float*)d_in[16];
    const float* Rb1 = (const float*)d_in[17];
    const float* R2  = (const float*)d_in[18];
    const float* Rb2 = (const float*)d_in[19];
    const float* R3  = (const float*)d_in[20];
    const float* Rb3 = (const float*)d_in[21];

    char* w = (char*)d_ws;
    size_t off = 0;
    auto alloc = [&](size_t bytes) {
        char* p = w + off;
        off += (bytes + 255) & ~(size_t)255;
        return p;
    };
    float*          path_state = (float*)alloc((size_t)NP * DIM * 4);
    float*          link_state = (float*)alloc((size_t)NLINKS * DIM * 4);
    float*          msg        = (float*)alloc((size_t)NLINKS * DIM * 4);
    float*          m          = (float*)alloc((size_t)E_TOT * DIM * 4);
    unsigned short* ls_hi      = (unsigned short*)alloc((size_t)NLINKS * DIM * 2);
    unsigned short* ls_lo      = (unsigned short*)alloc((size_t)NLINKS * DIM * 2);
    unsigned short* wfr        = (unsigned short*)alloc(4 * 3072 * 2);
    unsigned short* rfr        = (unsigned short*)alloc((size_t)(8192 + 65536) * 2 * 2);
    int*            cnt        = (int*)alloc((size_t)NLINKS * 4);
    int*            row_start  = (int*)alloc((size_t)(NLINKS + 1) * 4);
    int*            cursor     = (int*)alloc((size_t)NLINKS * 4);
    int*            slot       = (int*)alloc((size_t)E_TOT * 4);

    init_kernel<<<(NP + 255) / 256, 256, 0, stream>>>(cap, pol, wts, bw, tos, pk, avg,
                                                      link_state, path_state, ls_hi, ls_lo);
    hipMemsetAsync(cnt, 0, (size_t)NLINKS * 4, stream);
    csr_count  <<<(E_TOT + 255) / 256, 256, 0, stream>>>(links, cnt);
    csr_scan   <<<1, 256, 0, stream>>>(cnt, row_start, cursor);
    csr_scatter<<<(E_TOT + 255) / 256, 256, 0, stream>>>(links, cursor, slot);
    wprep_kernel<<<12, 256, 0, stream>>>(Wp, Up, wfr);
    rprep_kernel<<<(8192 + 65536 + 255) / 256, 256, 0, stream>>>(R1, R2, rfr);

    const int PGRID = (NP / 16 + 3) / 4;
    for (int it = 0; it < TITERS; ++it) {
        if (it < TITERS - 1) {
            path_kernel<true><<<PGRID, 256, 0, stream>>>(links, wfr, bp, ls_hi, ls_lo,
                                                         slot, path_state, m);
            agg_kernel <<<(NLINKS * 64 + 255) / 256, 256, 0, stream>>>(row_start, m, msg);
            link_kernel<<<(NLINKS + 255) / 256, 256, 0, stream>>>(Wl, Ul, bl, msg,
                                                                  link_state, ls_hi, ls_lo);
        } else {
            path_kernel<false><<<PGRID, 256, 0, stream>>>(links, wfr, bp, ls_hi, ls_lo,
                                                          slot, path_state, m);
        }
    }
    readout_kernel<<<(NP / 16 + 1) / 2, 128, 0, stream>>>(path_state, rfr, Rb1, Rb2,
                                                          R3, Rb3, (float*)d_out);
}